// Round 14
// baseline (179.206 us; speedup 1.0000x reference)
//
#include <hip/hip_runtime.h>
#include <hip/hip_bf16.h>

namespace {

constexpr int NB  = 16;
constexpr int NC  = 256;
constexpr int NHW = 16384;
constexpr int NK  = 1024;
constexpr int IGN = 255;
constexpr float SCALE = 4.5398164f;   // sqrt((1/0.07) * log2(e))
constexpr float CBIAS = 20.609929f;   // (1/0.07) * log2(e)
constexpr float LN2   = 0.69314718f;

typedef __attribute__((ext_vector_type(8))) short short8;
typedef __attribute__((ext_vector_type(4))) float f32x4;
typedef unsigned int u32;

#define ASM_VMCNT8 asm volatile("s_waitcnt vmcnt(8)" ::: "memory")
#define ASM_VMCNT0 asm volatile("s_waitcnt vmcnt(0)" ::: "memory")
#define ASM_LGKM0  asm volatile("s_waitcnt lgkmcnt(0)" ::: "memory")
#define SCHEDB     __builtin_amdgcn_sched_barrier(0)
#define MEMFENCE   asm volatile("" ::: "memory")
#define BARRIER    __builtin_amdgcn_s_barrier()
#define ACQ_AGENT  __builtin_amdgcn_fence(__ATOMIC_ACQUIRE, "agent")

__device__ __forceinline__ float fexp2(float x) { return __builtin_exp2f(x); }

__device__ __forceinline__ void gl_lds16(const void* g, void* l) {
  __builtin_amdgcn_global_load_lds((const __attribute__((address_space(1))) u32*)g,
                                   (__attribute__((address_space(3))) u32*)l, 16, 0, 0);
}

// ---------------------------------------------------------------- kernel 1
__global__ __launch_bounds__(1024) void pcl_sample(const int* __restrict__ labels,
                                                   int* __restrict__ sel_lab,
                                                   int* __restrict__ sel_idx,
                                                   int* __restrict__ cnt,
                                                   int* __restrict__ findone) {
  const int b = blockIdx.x, t = threadIdx.x, lane = t & 63, w = t >> 6;  // 16 waves
  if (t == 0) { cnt[b] = 0; if (b == 0) *findone = 0; }
  __shared__ int labL[1024 * 17];     // 68 KB
  __shared__ int wtot[16];

  sel_lab[b * NK + t] = IGN;

  const int* lab = labels + b * NHW;
#pragma unroll
  for (int k = 0; k < 16; ++k) {
    int idx = k * 1024 + t;
    labL[(idx >> 4) * 17 + (idx & 15)] = lab[idx];
  }
  __syncthreads();

  int cfg = 0, cbg = 0;
#pragma unroll
  for (int i = 0; i < 16; ++i) {
    int L = labL[t * 17 + i];
    cfg += (L != IGN && L != 0);
    cbg += (L == 0);
  }
  int packed = cfg | (cbg << 15);
  int incl = packed;
#pragma unroll
  for (int off = 1; off < 64; off <<= 1) {
    int n = __shfl_up(incl, off);
    if (lane >= off) incl += n;
  }
  if (lane == 63) wtot[w] = incl;
  __syncthreads();
  int wb = 0, total = 0;
#pragma unroll
  for (int ww = 0; ww < 16; ++ww) { int v = wtot[ww]; total += v; if (ww < w) wb += v; }
  int excl = incl - packed + wb;
  int rf  = excl & 32767;
  int rbg = (excl >> 15) & 32767;
  const int nfg = total & 32767;
  if (rf < NK || nfg + rbg < NK) {
#pragma unroll
    for (int i = 0; i < 16; ++i) {
      int L = labL[t * 17 + i];
      if (L == IGN) continue;
      if (L != 0) {
        if (rf < NK) { sel_lab[b * NK + rf] = L; sel_idx[b * NK + rf] = t * 16 + i; }
        ++rf;
      } else {
        int s = nfg + rbg;
        if (s < NK) { sel_lab[b * NK + s] = L; sel_idx[b * NK + s] = t * 16 + i; }
        ++rbg;
      }
    }
  }
}

// ---------------------------------------------------------------- kernel 2
__global__ __launch_bounds__(1024) void pcl_gather(const float* __restrict__ feats,
                                                   const int* __restrict__ sel_lab,
                                                   const int* __restrict__ sel_idx,
                                                   unsigned short* __restrict__ SF) {
  const int b = blockIdx.x >> 4, kb = blockIdx.x & 15;
  const int t = threadIdx.x, s = t & 63, w = t >> 6;
  __shared__ float fbuf[64][257];
  __shared__ float sqs[16][64];
  __shared__ float rn[64];
  const int gk = b * NK + kb * 64 + s;
  const int lb = sel_lab[gk];
  const int p = (lb != IGN) ? sel_idx[gk] : -1;
  const float* fb = feats + (size_t)b * NC * NHW;
  float sq = 0.f;
#pragma unroll
  for (int cc = 0; cc < 16; ++cc) {
    int c = w * 16 + cc;
    float v = (p >= 0) ? fb[(size_t)c * NHW + p] : 0.f;
    fbuf[s][c] = v;
    sq += v * v;
  }
  sqs[w][s] = sq;
  __syncthreads();
  if (t < 64) {
    float tot = 0.f;
#pragma unroll
    for (int k2 = 0; k2 < 16; ++k2) tot += sqs[k2][t];
    rn[t] = SCALE / fmaxf(sqrtf(tot), 1e-12f);
  }
  __syncthreads();
#pragma unroll
  for (int it = 0; it < 2; ++it) {
    int slot = it * 1024 + t;
    int ss = slot >> 5, ch = slot & 31;
    float r = rn[ss];
    short8 v8;
#pragma unroll
    for (int e = 0; e < 8; ++e) {
      float x = fbuf[ss][ch * 8 + e] * r;
      __hip_bfloat16 h = __float2bfloat16(x);
      unsigned short u; __builtin_memcpy(&u, &h, 2);
      v8[e] = (short)u;
    }
    *(short8*)(SF + ((size_t)(b * NK + kb * 64 + ss)) * NC + ch * 8) = v8;
  }
}

// ---------------------------------------------------------------- kernel 3
// R13 structure with a ONE-ROUND SOFTWARE-PIPELINED EPILOGUE (T15): round r's
// body runs ds_read+MFMA(r) then the VALU epilogue of round r-1 (independent
// of the in-flight MFMAs -> the scheduler interleaves VALU with the matrix
// pipe). accP/clP carry round r-1's results; static indices only.
__global__ __launch_bounds__(512) void pcl_tiles(
    const unsigned short* __restrict__ SF, const int* __restrict__ sel_lab,
    float2* __restrict__ SNd, float4* __restrict__ Rii, float4* __restrict__ Cp,
    float2* __restrict__ A1arr, float2* __restrict__ Aimg,
    int* __restrict__ cnt, int* __restrict__ findone, float* __restrict__ out) {
  const int id = blockIdx.x;
  const int i = id & 15, strip = id >> 4;
  const int inxt = (i + 1) & 15, iprev = (i + 15) & 15;
  const int t = threadIdx.x, lane = t & 63, w = t >> 6;
  const int rw = w & 1, ch4 = w >> 1;
  const int lg = lane >> 4, lr = lane & 15;
  const float SFAC = __builtin_exp2f(-CBIAS);

  __shared__ short buf[2][128 * 256];          // 128 KB
  __shared__ int labLds[2048];                 // 8 KB
  __shared__ float4 colAcc[2][128];            // 4 KB
  __shared__ float4 rredS[4][64];              // 4 KB
  __shared__ float4 rredX[4][64];              // 4 KB
  __shared__ float2 fold2[8];
  __shared__ int fA, fB;

  const unsigned short* SFrow = SF + (size_t)i * (NK * NC) + strip * 64 * NC;

  auto stage_round = [&](int rr) {
    const unsigned short* base =
        SF + (size_t)((rr < 8) ? i : inxt) * (NK * NC) + ((rr & 7) * 128) * NC;
    short* dst = buf[rr & 1];
#pragma unroll
    for (int it = 0; it < 8; ++it) {
      int n = it * 512 + t, row = n >> 5, ch = n & 31;
      gl_lds16(base + row * NC + ((ch ^ (row & 15)) << 3), dst + (size_t)n * 8);
    }
  };

  // ---- prologue: rows -> buf0, labels -> LDS ----
#pragma unroll
  for (int it = 0; it < 4; ++it) {
    int n = it * 512 + t, row = n >> 5, ch = n & 31;
    gl_lds16(SFrow + row * NC + ((ch ^ (row & 15)) << 3), buf[0] + (size_t)n * 8);
  }
  labLds[t] = sel_lab[i * NK + t];
  labLds[512 + t] = sel_lab[i * NK + 512 + t];
  labLds[1024 + t] = sel_lab[inxt * NK + t];
  labLds[1536 + t] = sel_lab[inxt * NK + 512 + t];
  ASM_VMCNT0; ASM_LGKM0; MEMFENCE; BARRIER; MEMFENCE;

  short8 afrag[2][8];
#pragma unroll
  for (int rt = 0; rt < 2; ++rt) {
    const int arow = rw * 32 + rt * 16 + lr;
#pragma unroll
    for (int ks = 0; ks < 8; ++ks) {
      int ch = ks * 4 + lg;
      afrag[rt][ks] = *(const short8*)(buf[0] + arow * 256 + ((ch ^ (arow & 15)) << 3));
    }
  }
  int rlab[2][4];
#pragma unroll
  for (int rt = 0; rt < 2; ++rt)
#pragma unroll
    for (int jj = 0; jj < 4; ++jj) {
      int L = labLds[strip * 64 + rw * 32 + rt * 16 + 4 * lg + jj];
      rlab[rt][jj] = (L == IGN) ? -1 : L;
    }
  ASM_LGKM0; SCHEDB; MEMFENCE; BARRIER; MEMFENCE;   // buf0 free

  stage_round(0);
  stage_round(1);

  ASM_VMCNT8; MEMFENCE; BARRIER; MEMFENCE;     // round 0 ready

  float SA[2][4], NPr[2][4], PEr[2][4], ETr[2][4];
  float SX[2][4], NX[2][4], PX[2][4];
#pragma unroll
  for (int rt = 0; rt < 2; ++rt)
#pragma unroll
    for (int jj = 0; jj < 4; ++jj) {
      SA[rt][jj] = 0.f; NPr[rt][jj] = 0.f; PEr[rt][jj] = 0.f; ETr[rt][jj] = 0.f;
      SX[rt][jj] = 0.f; NX[rt][jj] = 0.f; PX[rt][jj] = 0.f;
    }

  const int rs = strip >> 1;                    // diag round
  const bool dwave = ((ch4 >> 1) == (strip & 1));

  float accP[2][2][4];
  int clP[2] = {-2, -2};
  float cvfP[2] = {0.f, 0.f};
  float cSp[2], cNp[2], cEp[2];

  auto epi_self = [&](int rp) {
    const bool isdiag = (rp == rs) && dwave;
#pragma unroll
    for (int rt = 0; rt < 2; ++rt)
#pragma unroll
      for (int c2 = 0; c2 < 2; ++c2) {
        const int clc = clP[c2]; const float cvc = cvfP[c2];
        const int gc = rp * 128 + ch4 * 32 + c2 * 16 + lr;
        const int grb = strip * 64 + rw * 32 + rt * 16 + 4 * lg;
#pragma unroll
        for (int jj = 0; jj < 4; ++jj) {
          float a = accP[rt][c2][jj];
          float E = fexp2(a);
          float Ev = cvc * E;
          float pm = (rlab[rt][jj] == clc) ? 1.f : 0.f;
          if (isdiag) {
            bool ok = (grb + jj) != gc;
            pm = ok ? pm : 0.f;
            Ev = ok ? Ev : 0.f;
          }
          SA[rt][jj] += pm * a; NPr[rt][jj] += pm;
          PEr[rt][jj] += pm * Ev; ETr[rt][jj] += Ev;
        }
      }
  };

  auto epi_cross = [&]() {   // consumes accP/clP; writes cSp/cNp/cEp + colAcc
#pragma unroll
    for (int c2 = 0; c2 < 2; ++c2) { cSp[c2] = 0.f; cNp[c2] = 0.f; cEp[c2] = 0.f; }
#pragma unroll
    for (int rt = 0; rt < 2; ++rt)
#pragma unroll
      for (int c2 = 0; c2 < 2; ++c2) {
        const int clc = clP[c2];
#pragma unroll
        for (int jj = 0; jj < 4; ++jj) {
          float a = accP[rt][c2][jj];
          float E = fexp2(a);
          float pm = (rlab[rt][jj] == clc) ? 1.f : 0.f;
          float pa = pm * a, pe = pm * E;
          SX[rt][jj] += pa; NX[rt][jj] += pm; PX[rt][jj] += pe;
          cSp[c2] += pa; cNp[c2] += pm; cEp[c2] += pe;
        }
      }
#pragma unroll
    for (int c2 = 0; c2 < 2; ++c2) {
      cSp[c2] += __shfl_xor(cSp[c2], 16); cSp[c2] += __shfl_xor(cSp[c2], 32);
      cNp[c2] += __shfl_xor(cNp[c2], 16); cNp[c2] += __shfl_xor(cNp[c2], 32);
      cEp[c2] += __shfl_xor(cEp[c2], 16); cEp[c2] += __shfl_xor(cEp[c2], 32);
      if (lg == 0) colAcc[rw][ch4 * 32 + c2 * 16 + lr] = make_float4(cSp[c2], cNp[c2], cEp[c2], 0.f);
    }
  };

  auto cp_store = [&](int rp) {   // after a barrier; rp is a cross round
    if (rw == 1 && lg == 0) {
#pragma unroll
      for (int c2 = 0; c2 < 2; ++c2) {
        int col = ch4 * 32 + c2 * 16 + lr;
        float4 o = colAcc[0][col];
        Cp[(i * 16 + strip) * NK + (rp & 7) * 128 + col] =
            make_float4(cSp[c2] + o.x, cNp[c2] + o.y, (cEp[c2] + o.z) * SFAC, 0.f);
      }
    }
  };

  // ================= 16 rounds, epilogue pipelined by one =================
  for (int r = 0; r < 16; ++r) {
    int cl[2]; float cvf[2];
#pragma unroll
    for (int c2 = 0; c2 < 2; ++c2) {
      int L = labLds[((r < 8) ? 0 : 1024) + (r & 7) * 128 + ch4 * 32 + c2 * 16 + lr];
      cl[c2] = (L == IGN) ? -2 : L;
      cvf[c2] = (L == IGN) ? 0.f : 1.f;
    }

    const short* bb = buf[r & 1];
    f32x4 acc[2][2];
#pragma unroll
    for (int rt = 0; rt < 2; ++rt)
#pragma unroll
      for (int c2 = 0; c2 < 2; ++c2) acc[rt][c2] = f32x4{0.f, 0.f, 0.f, 0.f};
#pragma unroll
    for (int ks = 0; ks < 8; ++ks) {
      int ch = ks * 4 + lg;
      short8 b0, b1;
      {
        int br0 = ch4 * 32 + lr, br1 = ch4 * 32 + 16 + lr;
        b0 = *(const short8*)(bb + br0 * 256 + ((ch ^ (br0 & 15)) << 3));
        b1 = *(const short8*)(bb + br1 * 256 + ((ch ^ (br1 & 15)) << 3));
      }
      acc[0][0] = __builtin_amdgcn_mfma_f32_16x16x32_bf16(afrag[0][ks], b0, acc[0][0], 0, 0, 0);
      acc[0][1] = __builtin_amdgcn_mfma_f32_16x16x32_bf16(afrag[0][ks], b1, acc[0][1], 0, 0, 0);
      acc[1][0] = __builtin_amdgcn_mfma_f32_16x16x32_bf16(afrag[1][ks], b0, acc[1][0], 0, 0, 0);
      acc[1][1] = __builtin_amdgcn_mfma_f32_16x16x32_bf16(afrag[1][ks], b1, acc[1][1], 0, 0, 0);
    }

    // ---- deferred epilogue for round r-1 (independent of acc(r)) ----
    if (r >= 1) {
      if (r <= 8) epi_self(r - 1);
      else        epi_cross();
    }

    // ---- save this round's state for its (deferred) epilogue ----
#pragma unroll
    for (int rt = 0; rt < 2; ++rt)
#pragma unroll
      for (int c2 = 0; c2 < 2; ++c2)
#pragma unroll
        for (int jj = 0; jj < 4; ++jj) accP[rt][c2][jj] = acc[rt][c2][jj];
    clP[0] = cl[0]; clP[1] = cl[1];
    cvfP[0] = cvf[0]; cvfP[1] = cvf[1];

    ASM_LGKM0; SCHEDB;
    MEMFENCE; BARRIER; MEMFENCE;               // barrier1: buf[r&1] free, colAcc visible
    if (r >= 9) cp_store(r - 1);
    if (r < 14)      { stage_round(r + 2); ASM_VMCNT8; }
    else if (r == 14) { ASM_VMCNT0; }
    MEMFENCE; BARRIER; MEMFENCE;               // barrier2
  }

  // ---- drain: epilogue + Cp store for round 15 ----
  epi_cross();
  ASM_LGKM0; SCHEDB; MEMFENCE; BARRIER; MEMFENCE;
  cp_store(15);

  // ---- self fold -> rredS, cross fold -> rredX ----
#pragma unroll
  for (int rt = 0; rt < 2; ++rt)
#pragma unroll
    for (int jj = 0; jj < 4; ++jj) {
      float a = SA[rt][jj], b4 = NPr[rt][jj], c4 = PEr[rt][jj], d4 = ETr[rt][jj];
      float x = SX[rt][jj], y4 = NX[rt][jj], z4 = PX[rt][jj];
#pragma unroll
      for (int m = 1; m <= 8; m <<= 1) {
        a += __shfl_xor(a, m); b4 += __shfl_xor(b4, m);
        c4 += __shfl_xor(c4, m); d4 += __shfl_xor(d4, m);
        x += __shfl_xor(x, m); y4 += __shfl_xor(y4, m); z4 += __shfl_xor(z4, m);
      }
      if (lr == 0) {
        rredS[ch4][rw * 32 + rt * 16 + 4 * lg + jj] = make_float4(a, b4, c4, d4);
        rredX[ch4][rw * 32 + rt * 16 + 4 * lg + jj] = make_float4(x, y4, z4, 0.f);
      }
    }
  __syncthreads();

  // ---- per-row pass: SNd/Rii writes + local a1 ----
  if (t < 64) {
    float4 sS = rredS[0][t], sX = rredX[0][t];
#pragma unroll
    for (int c4 = 1; c4 < 4; ++c4) {
      float4 u = rredS[c4][t], v = rredX[c4][t];
      sS.x += u.x; sS.y += u.y; sS.z += u.z; sS.w += u.w;
      sX.x += v.x; sX.y += v.y; sX.z += v.z;
    }
    float SNL = sS.w - sS.z;
    float SN = SNL * SFAC + 1e-8f;
    float LSN = __logf(SN), rSN = 1.f / SN;
    int g = i * NK + strip * 64 + t;
    SNd[g] = make_float2(LSN, rSN);
    Rii[g] = make_float4(sS.x, sS.y, sS.z * SFAC, 0.f);
    float pps = LN2 * (sS.x - CBIAS * sS.y) - sS.y * LSN - rSN * (sS.z * SFAC);
    float ppx = LN2 * (sX.x - CBIAS * sX.y) - sX.y * LSN - rSN * (sX.z * SFAC);
    float np1 = sS.y + sX.y;
    float an = 0.f, ac = 0.f;
    if (np1 > 0.f) { an = -(pps + ppx) / np1; ac = 1.f; }
#pragma unroll
    for (int m = 1; m <= 32; m <<= 1) { an += __shfl_xor(an, m); ac += __shfl_xor(ac, m); }
    if (t == 0) A1arr[i * 16 + strip] = make_float2(an, ac);
  }
  __syncthreads();

  // ---- counter dance ----
  if (t == 0) {
    __threadfence();
    int o1 = atomicAdd(&cnt[i], 1);
    int o2 = atomicAdd(&cnt[iprev], 1);
    fA = (o1 == 31); fB = (o2 == 31);
  }
  __syncthreads();

  auto pair_fold = [&](int p) {
    const int q = (p + 1) & 15;
    ACQ_AGENT;
    float an = 0.f, ac = 0.f;
    for (int r2 = t; r2 < NK; r2 += 512) {
      float4 rii = Rii[q * NK + r2];
      float2 sn = SNd[q * NK + r2];
      float cs = 0.f, cn = 0.f, ce = 0.f;
#pragma unroll
      for (int s2 = 0; s2 < 16; ++s2) {
        float4 c = Cp[(p * 16 + s2) * NK + r2];
        cs += c.x; cn += c.y; ce += c.z;
      }
      float ppc = LN2 * (cs - CBIAS * cn) - cn * sn.x - sn.y * ce;
      float ppi = LN2 * (rii.x - CBIAS * rii.y) - rii.y * sn.x - sn.y * rii.z;
      float np2 = rii.y + cn;
      if (np2 > 0.f) { an -= (ppi + ppc) / np2; ac += 1.f; }
    }
#pragma unroll
    for (int m = 1; m <= 32; m <<= 1) { an += __shfl_xor(an, m); ac += __shfl_xor(ac, m); }
    if (lane == 0) fold2[w] = make_float2(an, ac);
    __syncthreads();
    if (t == 0) {
      float a2n = 0.f, a2c = 0.f;
#pragma unroll
      for (int k2 = 0; k2 < 8; ++k2) { a2n += fold2[k2].x; a2c += fold2[k2].y; }
      float a1n = 0.f, a1c = 0.f;
#pragma unroll
      for (int s2 = 0; s2 < 16; ++s2) {
        float2 a = A1arr[q * 16 + s2];
        a1n += a.x; a1c += a.y;
      }
      Aimg[q] = make_float2(a1n + a2n, a1c + a2c);
      __threadfence();
      int f = atomicAdd(findone, 1);
      if (f == NB - 1) {
        ACQ_AGENT;
        float v = 0.f;
#pragma unroll
        for (int im = 0; im < NB; ++im) {
          float2 gg = Aimg[im];
          v += gg.x / fmaxf(gg.y, 1.f);
        }
        out[0] = v / (float)NB;
      }
    }
    __syncthreads();
  };

  if (fA) pair_fold(i);
  if (fB) pair_fold(iprev);
}

}  // namespace

extern "C" void kernel_launch(void* const* d_in, const int* in_sizes, int n_in,
                              void* d_out, int out_size, void* d_ws, size_t ws_size,
                              hipStream_t stream) {
  (void)in_sizes; (void)n_in; (void)out_size; (void)ws_size;
  const float* feats  = (const float*)d_in[0];
  const int*   labels = (const int*)d_in[1];
  float* out = (float*)d_out;
  char* ws = (char*)d_ws;

  int* sel_lab = (int*)ws;                                       // 64 KB
  int* sel_idx = (int*)(ws + (64 << 10));                        // 64 KB
  unsigned short* SF = (unsigned short*)(ws + (128 << 10));      // 8 MB
  size_t off = (128 << 10) + (size_t)NB * NK * NC * 2;
  float2* SNd = (float2*)(ws + off);  off += (size_t)NB * NK * 8;       // 128 KB
  float4* Rii = (float4*)(ws + off);  off += (size_t)NB * NK * 16;      // 256 KB
  float4* Cp  = (float4*)(ws + off);  off += (size_t)NB * 16 * NK * 16; // 4 MB
  float2* A1arr = (float2*)(ws + off); off += (size_t)NB * 16 * 8;
  float2* Aimg = (float2*)(ws + off);  off += NB * 8;
  int* cnt = (int*)(ws + off);         off += 16 * 4;
  int* findone = (int*)(ws + off);

  pcl_sample<<<NB, 1024, 0, stream>>>(labels, sel_lab, sel_idx, cnt, findone);
  pcl_gather<<<256, 1024, 0, stream>>>(feats, sel_lab, sel_idx, SF);
  pcl_tiles<<<256, 512, 0, stream>>>(SF, sel_lab, SNd, Rii, Cp,
                                     A1arr, Aimg, cnt, findone, out);
}

// Round 15
// 178.616 us; speedup vs baseline: 1.0033x; 1.0033x over previous
//
#include <hip/hip_runtime.h>
#include <hip/hip_bf16.h>

namespace {

constexpr int NB  = 16;
constexpr int NC  = 256;
constexpr int NHW = 16384;
constexpr int NK  = 1024;
constexpr int IGN = 255;
constexpr float SCALE = 4.5398164f;   // sqrt((1/0.07) * log2(e))
constexpr float CBIAS = 20.609929f;   // (1/0.07) * log2(e)
constexpr float LN2   = 0.69314718f;

typedef __attribute__((ext_vector_type(8))) short short8;
typedef __attribute__((ext_vector_type(4))) float f32x4;
typedef unsigned int u32;

#define ASM_VMCNT8 asm volatile("s_waitcnt vmcnt(8)" ::: "memory")
#define ASM_VMCNT0 asm volatile("s_waitcnt vmcnt(0)" ::: "memory")
#define ASM_LGKM0  asm volatile("s_waitcnt lgkmcnt(0)" ::: "memory")
#define SCHEDB     __builtin_amdgcn_sched_barrier(0)
#define MEMFENCE   asm volatile("" ::: "memory")
#define BARRIER    __builtin_amdgcn_s_barrier()
#define ACQ_AGENT  __builtin_amdgcn_fence(__ATOMIC_ACQUIRE, "agent")

__device__ __forceinline__ float fexp2(float x) { return __builtin_exp2f(x); }

__device__ __forceinline__ void gl_lds16(const void* g, void* l) {
  __builtin_amdgcn_global_load_lds((const __attribute__((address_space(1))) u32*)g,
                                   (__attribute__((address_space(3))) u32*)l, 16, 0, 0);
}

// ---------------------------------------------------------------- kernel 1
__global__ __launch_bounds__(1024) void pcl_sample(const int* __restrict__ labels,
                                                   int* __restrict__ sel_lab,
                                                   int* __restrict__ sel_idx,
                                                   int* __restrict__ cnt,
                                                   int* __restrict__ findone) {
  const int b = blockIdx.x, t = threadIdx.x, lane = t & 63, w = t >> 6;  // 16 waves
  if (t == 0) { cnt[b] = 0; if (b == 0) *findone = 0; }
  __shared__ int labL[1024 * 17];     // 68 KB
  __shared__ int wtot[16];

  sel_lab[b * NK + t] = IGN;

  const int* lab = labels + b * NHW;
#pragma unroll
  for (int k = 0; k < 16; ++k) {
    int idx = k * 1024 + t;
    labL[(idx >> 4) * 17 + (idx & 15)] = lab[idx];
  }
  __syncthreads();

  int cfg = 0, cbg = 0;
#pragma unroll
  for (int i = 0; i < 16; ++i) {
    int L = labL[t * 17 + i];
    cfg += (L != IGN && L != 0);
    cbg += (L == 0);
  }
  int packed = cfg | (cbg << 15);
  int incl = packed;
#pragma unroll
  for (int off = 1; off < 64; off <<= 1) {
    int n = __shfl_up(incl, off);
    if (lane >= off) incl += n;
  }
  if (lane == 63) wtot[w] = incl;
  __syncthreads();
  int wb = 0, total = 0;
#pragma unroll
  for (int ww = 0; ww < 16; ++ww) { int v = wtot[ww]; total += v; if (ww < w) wb += v; }
  int excl = incl - packed + wb;
  int rf  = excl & 32767;
  int rbg = (excl >> 15) & 32767;
  const int nfg = total & 32767;
  if (rf < NK || nfg + rbg < NK) {
#pragma unroll
    for (int i = 0; i < 16; ++i) {
      int L = labL[t * 17 + i];
      if (L == IGN) continue;
      if (L != 0) {
        if (rf < NK) { sel_lab[b * NK + rf] = L; sel_idx[b * NK + rf] = t * 16 + i; }
        ++rf;
      } else {
        int s = nfg + rbg;
        if (s < NK) { sel_lab[b * NK + s] = L; sel_idx[b * NK + s] = t * 16 + i; }
        ++rbg;
      }
    }
  }
}

// ---------------------------------------------------------------- kernel 2
__global__ __launch_bounds__(1024) void pcl_gather(const float* __restrict__ feats,
                                                   const int* __restrict__ sel_lab,
                                                   const int* __restrict__ sel_idx,
                                                   unsigned short* __restrict__ SF) {
  const int b = blockIdx.x >> 4, kb = blockIdx.x & 15;
  const int t = threadIdx.x, s = t & 63, w = t >> 6;
  __shared__ float fbuf[64][257];
  __shared__ float sqs[16][64];
  __shared__ float rn[64];
  const int gk = b * NK + kb * 64 + s;
  const int lb = sel_lab[gk];
  const int p = (lb != IGN) ? sel_idx[gk] : -1;
  const float* fb = feats + (size_t)b * NC * NHW;
  float sq = 0.f;
#pragma unroll
  for (int cc = 0; cc < 16; ++cc) {
    int c = w * 16 + cc;
    float v = (p >= 0) ? fb[(size_t)c * NHW + p] : 0.f;
    fbuf[s][c] = v;
    sq += v * v;
  }
  sqs[w][s] = sq;
  __syncthreads();
  if (t < 64) {
    float tot = 0.f;
#pragma unroll
    for (int k2 = 0; k2 < 16; ++k2) tot += sqs[k2][t];
    rn[t] = SCALE / fmaxf(sqrtf(tot), 1e-12f);
  }
  __syncthreads();
#pragma unroll
  for (int it = 0; it < 2; ++it) {
    int slot = it * 1024 + t;
    int ss = slot >> 5, ch = slot & 31;
    float r = rn[ss];
    short8 v8;
#pragma unroll
    for (int e = 0; e < 8; ++e) {
      float x = fbuf[ss][ch * 8 + e] * r;
      __hip_bfloat16 h = __float2bfloat16(x);
      unsigned short u; __builtin_memcpy(&u, &h, 2);
      v8[e] = (short)u;
    }
    *(short8*)(SF + ((size_t)(b * NK + kb * 64 + ss)) * NC + ch * 8) = v8;
  }
}

// ---------------------------------------------------------------- kernel 3
// R14 pipelined-epilogue structure + __launch_bounds__(512, 2): occupancy is
// already LDS-limited to 8 waves/CU (2/SIMD), so declaring 2 waves/SIMD is
// free and raises the VGPR cap 128 -> 256, eliminating the scratch spill
// that destroyed R14 (242 MB scratch writes, VGPR pinned at 128).
__global__ __launch_bounds__(512, 2) void pcl_tiles(
    const unsigned short* __restrict__ SF, const int* __restrict__ sel_lab,
    float2* __restrict__ SNd, float4* __restrict__ Rii, float4* __restrict__ Cp,
    float2* __restrict__ A1arr, float2* __restrict__ Aimg,
    int* __restrict__ cnt, int* __restrict__ findone, float* __restrict__ out) {
  const int id = blockIdx.x;
  const int i = id & 15, strip = id >> 4;
  const int inxt = (i + 1) & 15, iprev = (i + 15) & 15;
  const int t = threadIdx.x, lane = t & 63, w = t >> 6;
  const int rw = w & 1, ch4 = w >> 1;
  const int lg = lane >> 4, lr = lane & 15;
  const float SFAC = __builtin_exp2f(-CBIAS);

  __shared__ short buf[2][128 * 256];          // 128 KB
  __shared__ int labLds[2048];                 // 8 KB
  __shared__ float4 colAcc[2][128];            // 4 KB
  __shared__ float4 rredS[4][64];              // 4 KB
  __shared__ float4 rredX[4][64];              // 4 KB
  __shared__ float2 fold2[8];
  __shared__ int fA, fB;

  const unsigned short* SFrow = SF + (size_t)i * (NK * NC) + strip * 64 * NC;

  auto stage_round = [&](int rr) {
    const unsigned short* base =
        SF + (size_t)((rr < 8) ? i : inxt) * (NK * NC) + ((rr & 7) * 128) * NC;
    short* dst = buf[rr & 1];
#pragma unroll
    for (int it = 0; it < 8; ++it) {
      int n = it * 512 + t, row = n >> 5, ch = n & 31;
      gl_lds16(base + row * NC + ((ch ^ (row & 15)) << 3), dst + (size_t)n * 8);
    }
  };

  // ---- prologue: rows -> buf0, labels -> LDS ----
#pragma unroll
  for (int it = 0; it < 4; ++it) {
    int n = it * 512 + t, row = n >> 5, ch = n & 31;
    gl_lds16(SFrow + row * NC + ((ch ^ (row & 15)) << 3), buf[0] + (size_t)n * 8);
  }
  labLds[t] = sel_lab[i * NK + t];
  labLds[512 + t] = sel_lab[i * NK + 512 + t];
  labLds[1024 + t] = sel_lab[inxt * NK + t];
  labLds[1536 + t] = sel_lab[inxt * NK + 512 + t];
  ASM_VMCNT0; ASM_LGKM0; MEMFENCE; BARRIER; MEMFENCE;

  short8 afrag[2][8];
#pragma unroll
  for (int rt = 0; rt < 2; ++rt) {
    const int arow = rw * 32 + rt * 16 + lr;
#pragma unroll
    for (int ks = 0; ks < 8; ++ks) {
      int ch = ks * 4 + lg;
      afrag[rt][ks] = *(const short8*)(buf[0] + arow * 256 + ((ch ^ (arow & 15)) << 3));
    }
  }
  int rlab[2][4];
#pragma unroll
  for (int rt = 0; rt < 2; ++rt)
#pragma unroll
    for (int jj = 0; jj < 4; ++jj) {
      int L = labLds[strip * 64 + rw * 32 + rt * 16 + 4 * lg + jj];
      rlab[rt][jj] = (L == IGN) ? -1 : L;
    }
  ASM_LGKM0; SCHEDB; MEMFENCE; BARRIER; MEMFENCE;   // buf0 free

  stage_round(0);
  stage_round(1);

  ASM_VMCNT8; MEMFENCE; BARRIER; MEMFENCE;     // round 0 ready

  float SA[2][4], NPr[2][4], PEr[2][4], ETr[2][4];
  float SX[2][4], NX[2][4], PX[2][4];
#pragma unroll
  for (int rt = 0; rt < 2; ++rt)
#pragma unroll
    for (int jj = 0; jj < 4; ++jj) {
      SA[rt][jj] = 0.f; NPr[rt][jj] = 0.f; PEr[rt][jj] = 0.f; ETr[rt][jj] = 0.f;
      SX[rt][jj] = 0.f; NX[rt][jj] = 0.f; PX[rt][jj] = 0.f;
    }

  const int rs = strip >> 1;                    // diag round
  const bool dwave = ((ch4 >> 1) == (strip & 1));

  float accP[2][2][4];
  int clP[2] = {-2, -2};
  float cvfP[2] = {0.f, 0.f};
  float cSp[2], cNp[2], cEp[2];

  auto epi_self = [&](int rp) {
    const bool isdiag = (rp == rs) && dwave;
#pragma unroll
    for (int rt = 0; rt < 2; ++rt)
#pragma unroll
      for (int c2 = 0; c2 < 2; ++c2) {
        const int clc = clP[c2]; const float cvc = cvfP[c2];
        const int gc = rp * 128 + ch4 * 32 + c2 * 16 + lr;
        const int grb = strip * 64 + rw * 32 + rt * 16 + 4 * lg;
#pragma unroll
        for (int jj = 0; jj < 4; ++jj) {
          float a = accP[rt][c2][jj];
          float E = fexp2(a);
          float Ev = cvc * E;
          float pm = (rlab[rt][jj] == clc) ? 1.f : 0.f;
          if (isdiag) {
            bool ok = (grb + jj) != gc;
            pm = ok ? pm : 0.f;
            Ev = ok ? Ev : 0.f;
          }
          SA[rt][jj] += pm * a; NPr[rt][jj] += pm;
          PEr[rt][jj] += pm * Ev; ETr[rt][jj] += Ev;
        }
      }
  };

  auto epi_cross = [&]() {   // consumes accP/clP; writes cSp/cNp/cEp + colAcc
#pragma unroll
    for (int c2 = 0; c2 < 2; ++c2) { cSp[c2] = 0.f; cNp[c2] = 0.f; cEp[c2] = 0.f; }
#pragma unroll
    for (int rt = 0; rt < 2; ++rt)
#pragma unroll
      for (int c2 = 0; c2 < 2; ++c2) {
        const int clc = clP[c2];
#pragma unroll
        for (int jj = 0; jj < 4; ++jj) {
          float a = accP[rt][c2][jj];
          float E = fexp2(a);
          float pm = (rlab[rt][jj] == clc) ? 1.f : 0.f;
          float pa = pm * a, pe = pm * E;
          SX[rt][jj] += pa; NX[rt][jj] += pm; PX[rt][jj] += pe;
          cSp[c2] += pa; cNp[c2] += pm; cEp[c2] += pe;
        }
      }
#pragma unroll
    for (int c2 = 0; c2 < 2; ++c2) {
      cSp[c2] += __shfl_xor(cSp[c2], 16); cSp[c2] += __shfl_xor(cSp[c2], 32);
      cNp[c2] += __shfl_xor(cNp[c2], 16); cNp[c2] += __shfl_xor(cNp[c2], 32);
      cEp[c2] += __shfl_xor(cEp[c2], 16); cEp[c2] += __shfl_xor(cEp[c2], 32);
      if (lg == 0) colAcc[rw][ch4 * 32 + c2 * 16 + lr] = make_float4(cSp[c2], cNp[c2], cEp[c2], 0.f);
    }
  };

  auto cp_store = [&](int rp) {   // after a barrier; rp is a cross round
    if (rw == 1 && lg == 0) {
#pragma unroll
      for (int c2 = 0; c2 < 2; ++c2) {
        int col = ch4 * 32 + c2 * 16 + lr;
        float4 o = colAcc[0][col];
        Cp[(i * 16 + strip) * NK + (rp & 7) * 128 + col] =
            make_float4(cSp[c2] + o.x, cNp[c2] + o.y, (cEp[c2] + o.z) * SFAC, 0.f);
      }
    }
  };

  // ================= 16 rounds, epilogue pipelined by one =================
  for (int r = 0; r < 16; ++r) {
    int cl[2]; float cvf[2];
#pragma unroll
    for (int c2 = 0; c2 < 2; ++c2) {
      int L = labLds[((r < 8) ? 0 : 1024) + (r & 7) * 128 + ch4 * 32 + c2 * 16 + lr];
      cl[c2] = (L == IGN) ? -2 : L;
      cvf[c2] = (L == IGN) ? 0.f : 1.f;
    }

    const short* bb = buf[r & 1];
    f32x4 acc[2][2];
#pragma unroll
    for (int rt = 0; rt < 2; ++rt)
#pragma unroll
      for (int c2 = 0; c2 < 2; ++c2) acc[rt][c2] = f32x4{0.f, 0.f, 0.f, 0.f};
#pragma unroll
    for (int ks = 0; ks < 8; ++ks) {
      int ch = ks * 4 + lg;
      short8 b0, b1;
      {
        int br0 = ch4 * 32 + lr, br1 = ch4 * 32 + 16 + lr;
        b0 = *(const short8*)(bb + br0 * 256 + ((ch ^ (br0 & 15)) << 3));
        b1 = *(const short8*)(bb + br1 * 256 + ((ch ^ (br1 & 15)) << 3));
      }
      acc[0][0] = __builtin_amdgcn_mfma_f32_16x16x32_bf16(afrag[0][ks], b0, acc[0][0], 0, 0, 0);
      acc[0][1] = __builtin_amdgcn_mfma_f32_16x16x32_bf16(afrag[0][ks], b1, acc[0][1], 0, 0, 0);
      acc[1][0] = __builtin_amdgcn_mfma_f32_16x16x32_bf16(afrag[1][ks], b0, acc[1][0], 0, 0, 0);
      acc[1][1] = __builtin_amdgcn_mfma_f32_16x16x32_bf16(afrag[1][ks], b1, acc[1][1], 0, 0, 0);
    }

    // ---- deferred epilogue for round r-1 (independent of acc(r)) ----
    if (r >= 1) {
      if (r <= 8) epi_self(r - 1);
      else        epi_cross();
    }

    // ---- save this round's state for its (deferred) epilogue ----
#pragma unroll
    for (int rt = 0; rt < 2; ++rt)
#pragma unroll
      for (int c2 = 0; c2 < 2; ++c2)
#pragma unroll
        for (int jj = 0; jj < 4; ++jj) accP[rt][c2][jj] = acc[rt][c2][jj];
    clP[0] = cl[0]; clP[1] = cl[1];
    cvfP[0] = cvf[0]; cvfP[1] = cvf[1];

    ASM_LGKM0; SCHEDB;
    MEMFENCE; BARRIER; MEMFENCE;               // barrier1: buf[r&1] free, colAcc visible
    if (r >= 9) cp_store(r - 1);
    if (r < 14)      { stage_round(r + 2); ASM_VMCNT8; }
    else if (r == 14) { ASM_VMCNT0; }
    MEMFENCE; BARRIER; MEMFENCE;               // barrier2
  }

  // ---- drain: epilogue + Cp store for round 15 ----
  epi_cross();
  ASM_LGKM0; SCHEDB; MEMFENCE; BARRIER; MEMFENCE;
  cp_store(15);

  // ---- self fold -> rredS, cross fold -> rredX ----
#pragma unroll
  for (int rt = 0; rt < 2; ++rt)
#pragma unroll
    for (int jj = 0; jj < 4; ++jj) {
      float a = SA[rt][jj], b4 = NPr[rt][jj], c4 = PEr[rt][jj], d4 = ETr[rt][jj];
      float x = SX[rt][jj], y4 = NX[rt][jj], z4 = PX[rt][jj];
#pragma unroll
      for (int m = 1; m <= 8; m <<= 1) {
        a += __shfl_xor(a, m); b4 += __shfl_xor(b4, m);
        c4 += __shfl_xor(c4, m); d4 += __shfl_xor(d4, m);
        x += __shfl_xor(x, m); y4 += __shfl_xor(y4, m); z4 += __shfl_xor(z4, m);
      }
      if (lr == 0) {
        rredS[ch4][rw * 32 + rt * 16 + 4 * lg + jj] = make_float4(a, b4, c4, d4);
        rredX[ch4][rw * 32 + rt * 16 + 4 * lg + jj] = make_float4(x, y4, z4, 0.f);
      }
    }
  __syncthreads();

  // ---- per-row pass: SNd/Rii writes + local a1 ----
  if (t < 64) {
    float4 sS = rredS[0][t], sX = rredX[0][t];
#pragma unroll
    for (int c4 = 1; c4 < 4; ++c4) {
      float4 u = rredS[c4][t], v = rredX[c4][t];
      sS.x += u.x; sS.y += u.y; sS.z += u.z; sS.w += u.w;
      sX.x += v.x; sX.y += v.y; sX.z += v.z;
    }
    float SNL = sS.w - sS.z;
    float SN = SNL * SFAC + 1e-8f;
    float LSN = __logf(SN), rSN = 1.f / SN;
    int g = i * NK + strip * 64 + t;
    SNd[g] = make_float2(LSN, rSN);
    Rii[g] = make_float4(sS.x, sS.y, sS.z * SFAC, 0.f);
    float pps = LN2 * (sS.x - CBIAS * sS.y) - sS.y * LSN - rSN * (sS.z * SFAC);
    float ppx = LN2 * (sX.x - CBIAS * sX.y) - sX.y * LSN - rSN * (sX.z * SFAC);
    float np1 = sS.y + sX.y;
    float an = 0.f, ac = 0.f;
    if (np1 > 0.f) { an = -(pps + ppx) / np1; ac = 1.f; }
#pragma unroll
    for (int m = 1; m <= 32; m <<= 1) { an += __shfl_xor(an, m); ac += __shfl_xor(ac, m); }
    if (t == 0) A1arr[i * 16 + strip] = make_float2(an, ac);
  }
  __syncthreads();

  // ---- counter dance ----
  if (t == 0) {
    __threadfence();
    int o1 = atomicAdd(&cnt[i], 1);
    int o2 = atomicAdd(&cnt[iprev], 1);
    fA = (o1 == 31); fB = (o2 == 31);
  }
  __syncthreads();

  auto pair_fold = [&](int p) {
    const int q = (p + 1) & 15;
    ACQ_AGENT;
    float an = 0.f, ac = 0.f;
    for (int r2 = t; r2 < NK; r2 += 512) {
      float4 rii = Rii[q * NK + r2];
      float2 sn = SNd[q * NK + r2];
      float cs = 0.f, cn = 0.f, ce = 0.f;
#pragma unroll
      for (int s2 = 0; s2 < 16; ++s2) {
        float4 c = Cp[(p * 16 + s2) * NK + r2];
        cs += c.x; cn += c.y; ce += c.z;
      }
      float ppc = LN2 * (cs - CBIAS * cn) - cn * sn.x - sn.y * ce;
      float ppi = LN2 * (rii.x - CBIAS * rii.y) - rii.y * sn.x - sn.y * rii.z;
      float np2 = rii.y + cn;
      if (np2 > 0.f) { an -= (ppi + ppc) / np2; ac += 1.f; }
    }
#pragma unroll
    for (int m = 1; m <= 32; m <<= 1) { an += __shfl_xor(an, m); ac += __shfl_xor(ac, m); }
    if (lane == 0) fold2[w] = make_float2(an, ac);
    __syncthreads();
    if (t == 0) {
      float a2n = 0.f, a2c = 0.f;
#pragma unroll
      for (int k2 = 0; k2 < 8; ++k2) { a2n += fold2[k2].x; a2c += fold2[k2].y; }
      float a1n = 0.f, a1c = 0.f;
#pragma unroll
      for (int s2 = 0; s2 < 16; ++s2) {
        float2 a = A1arr[q * 16 + s2];
        a1n += a.x; a1c += a.y;
      }
      Aimg[q] = make_float2(a1n + a2n, a1c + a2c);
      __threadfence();
      int f = atomicAdd(findone, 1);
      if (f == NB - 1) {
        ACQ_AGENT;
        float v = 0.f;
#pragma unroll
        for (int im = 0; im < NB; ++im) {
          float2 gg = Aimg[im];
          v += gg.x / fmaxf(gg.y, 1.f);
        }
        out[0] = v / (float)NB;
      }
    }
    __syncthreads();
  };

  if (fA) pair_fold(i);
  if (fB) pair_fold(iprev);
}

}  // namespace

extern "C" void kernel_launch(void* const* d_in, const int* in_sizes, int n_in,
                              void* d_out, int out_size, void* d_ws, size_t ws_size,
                              hipStream_t stream) {
  (void)in_sizes; (void)n_in; (void)out_size; (void)ws_size;
  const float* feats  = (const float*)d_in[0];
  const int*   labels = (const int*)d_in[1];
  float* out = (float*)d_out;
  char* ws = (char*)d_ws;

  int* sel_lab = (int*)ws;                                       // 64 KB
  int* sel_idx = (int*)(ws + (64 << 10));                        // 64 KB
  unsigned short* SF = (unsigned short*)(ws + (128 << 10));      // 8 MB
  size_t off = (128 << 10) + (size_t)NB * NK * NC * 2;
  float2* SNd = (float2*)(ws + off);  off += (size_t)NB * NK * 8;       // 128 KB
  float4* Rii = (float4*)(ws + off);  off += (size_t)NB * NK * 16;      // 256 KB
  float4* Cp  = (float4*)(ws + off);  off += (size_t)NB * 16 * NK * 16; // 4 MB
  float2* A1arr = (float2*)(ws + off); off += (size_t)NB * 16 * 8;
  float2* Aimg = (float2*)(ws + off);  off += NB * 8;
  int* cnt = (int*)(ws + off);         off += 16 * 4;
  int* findone = (int*)(ws + off);

  pcl_sample<<<NB, 1024, 0, stream>>>(labels, sel_lab, sel_idx, cnt, findone);
  pcl_gather<<<256, 1024, 0, stream>>>(feats, sel_lab, sel_idx, SF);
  pcl_tiles<<<256, 512, 0, stream>>>(SF, sel_lab, SNd, Rii, Cp,
                                     A1arr, Aimg, cnt, findone, out);
}

// Round 16
// 178.556 us; speedup vs baseline: 1.0036x; 1.0003x over previous
//
#include <hip/hip_runtime.h>
#include <hip/hip_bf16.h>

namespace {

constexpr int NB  = 16;
constexpr int NC  = 256;
constexpr int NHW = 16384;
constexpr int NK  = 1024;
constexpr int IGN = 255;
constexpr float SCALE = 4.5398164f;   // sqrt((1/0.07) * log2(e))
constexpr float CBIAS = 20.609929f;   // (1/0.07) * log2(e)
constexpr float LN2   = 0.69314718f;

typedef __attribute__((ext_vector_type(8))) short short8;
typedef __attribute__((ext_vector_type(4))) float f32x4;
typedef unsigned int u32;

#define ASM_VMCNT8 asm volatile("s_waitcnt vmcnt(8)" ::: "memory")
#define ASM_VMCNT0 asm volatile("s_waitcnt vmcnt(0)" ::: "memory")
#define ASM_LGKM0  asm volatile("s_waitcnt lgkmcnt(0)" ::: "memory")
#define SCHEDB     __builtin_amdgcn_sched_barrier(0)
#define MEMFENCE   asm volatile("" ::: "memory")
#define BARRIER    __builtin_amdgcn_s_barrier()
#define ACQ_AGENT  __builtin_amdgcn_fence(__ATOMIC_ACQUIRE, "agent")

__device__ __forceinline__ float fexp2(float x) { return __builtin_exp2f(x); }

__device__ __forceinline__ void gl_lds16(const void* g, void* l) {
  __builtin_amdgcn_global_load_lds((const __attribute__((address_space(1))) u32*)g,
                                   (__attribute__((address_space(3))) u32*)l, 16, 0, 0);
}

// ---------------------------------------------------------------- kernel 1
__global__ __launch_bounds__(1024) void pcl_sample(const int* __restrict__ labels,
                                                   int* __restrict__ sel_lab,
                                                   int* __restrict__ sel_idx,
                                                   int* __restrict__ cnt,
                                                   int* __restrict__ findone) {
  const int b = blockIdx.x, t = threadIdx.x, lane = t & 63, w = t >> 6;  // 16 waves
  if (t == 0) { cnt[b] = 0; if (b == 0) *findone = 0; }
  __shared__ int labL[1024 * 17];     // 68 KB
  __shared__ int wtot[16];

  sel_lab[b * NK + t] = IGN;

  const int* lab = labels + b * NHW;
#pragma unroll
  for (int k = 0; k < 16; ++k) {
    int idx = k * 1024 + t;
    labL[(idx >> 4) * 17 + (idx & 15)] = lab[idx];
  }
  __syncthreads();

  int cfg = 0, cbg = 0;
#pragma unroll
  for (int i = 0; i < 16; ++i) {
    int L = labL[t * 17 + i];
    cfg += (L != IGN && L != 0);
    cbg += (L == 0);
  }
  int packed = cfg | (cbg << 15);
  int incl = packed;
#pragma unroll
  for (int off = 1; off < 64; off <<= 1) {
    int n = __shfl_up(incl, off);
    if (lane >= off) incl += n;
  }
  if (lane == 63) wtot[w] = incl;
  __syncthreads();
  int wb = 0, total = 0;
#pragma unroll
  for (int ww = 0; ww < 16; ++ww) { int v = wtot[ww]; total += v; if (ww < w) wb += v; }
  int excl = incl - packed + wb;
  int rf  = excl & 32767;
  int rbg = (excl >> 15) & 32767;
  const int nfg = total & 32767;
  if (rf < NK || nfg + rbg < NK) {
#pragma unroll
    for (int i = 0; i < 16; ++i) {
      int L = labL[t * 17 + i];
      if (L == IGN) continue;
      if (L != 0) {
        if (rf < NK) { sel_lab[b * NK + rf] = L; sel_idx[b * NK + rf] = t * 16 + i; }
        ++rf;
      } else {
        int s = nfg + rbg;
        if (s < NK) { sel_lab[b * NK + s] = L; sel_idx[b * NK + s] = t * 16 + i; }
        ++rbg;
      }
    }
  }
}

// ---------------------------------------------------------------- kernel 2
__global__ __launch_bounds__(1024) void pcl_gather(const float* __restrict__ feats,
                                                   const int* __restrict__ sel_lab,
                                                   const int* __restrict__ sel_idx,
                                                   unsigned short* __restrict__ SF) {
  const int b = blockIdx.x >> 4, kb = blockIdx.x & 15;
  const int t = threadIdx.x, s = t & 63, w = t >> 6;
  __shared__ float fbuf[64][257];
  __shared__ float sqs[16][64];
  __shared__ float rn[64];
  const int gk = b * NK + kb * 64 + s;
  const int lb = sel_lab[gk];
  const int p = (lb != IGN) ? sel_idx[gk] : -1;
  const float* fb = feats + (size_t)b * NC * NHW;
  float sq = 0.f;
#pragma unroll
  for (int cc = 0; cc < 16; ++cc) {
    int c = w * 16 + cc;
    float v = (p >= 0) ? fb[(size_t)c * NHW + p] : 0.f;
    fbuf[s][c] = v;
    sq += v * v;
  }
  sqs[w][s] = sq;
  __syncthreads();
  if (t < 64) {
    float tot = 0.f;
#pragma unroll
    for (int k2 = 0; k2 < 16; ++k2) tot += sqs[k2][t];
    rn[t] = SCALE / fmaxf(sqrtf(tot), 1e-12f);
  }
  __syncthreads();
#pragma unroll
  for (int it = 0; it < 2; ++it) {
    int slot = it * 1024 + t;
    int ss = slot >> 5, ch = slot & 31;
    float r = rn[ss];
    short8 v8;
#pragma unroll
    for (int e = 0; e < 8; ++e) {
      float x = fbuf[ss][ch * 8 + e] * r;
      __hip_bfloat16 h = __float2bfloat16(x);
      unsigned short u; __builtin_memcpy(&u, &h, 2);
      v8[e] = (short)u;
    }
    *(short8*)(SF + ((size_t)(b * NK + kb * 64 + ss)) * NC + ch * 8) = v8;
  }
}

// ---------------------------------------------------------------- kernel 3
// R14 pipelined-epilogue structure + __launch_bounds__(512, 1).
// Evidence: (512,2) forced VGPR cap 128 (CUDA minBlocks mapping: 2 blocks x
// 8 waves / 4 SIMD = 4 waves/EU -> 128). (512,1) => 1 block/CU -> 2 waves/EU
// -> 256-VGPR cap; occupancy is LDS-limited to 1 block/CU anyway, so nothing
// is lost and the 242 MB scratch spill should vanish.
__global__ __launch_bounds__(512, 1) void pcl_tiles(
    const unsigned short* __restrict__ SF, const int* __restrict__ sel_lab,
    float2* __restrict__ SNd, float4* __restrict__ Rii, float4* __restrict__ Cp,
    float2* __restrict__ A1arr, float2* __restrict__ Aimg,
    int* __restrict__ cnt, int* __restrict__ findone, float* __restrict__ out) {
  const int id = blockIdx.x;
  const int i = id & 15, strip = id >> 4;
  const int inxt = (i + 1) & 15, iprev = (i + 15) & 15;
  const int t = threadIdx.x, lane = t & 63, w = t >> 6;
  const int rw = w & 1, ch4 = w >> 1;
  const int lg = lane >> 4, lr = lane & 15;
  const float SFAC = __builtin_exp2f(-CBIAS);

  __shared__ short buf[2][128 * 256];          // 128 KB
  __shared__ int labLds[2048];                 // 8 KB
  __shared__ float4 colAcc[2][128];            // 4 KB
  __shared__ float4 rredS[4][64];              // 4 KB
  __shared__ float4 rredX[4][64];              // 4 KB
  __shared__ float2 fold2[8];
  __shared__ int fA, fB;

  const unsigned short* SFrow = SF + (size_t)i * (NK * NC) + strip * 64 * NC;

  auto stage_round = [&](int rr) {
    const unsigned short* base =
        SF + (size_t)((rr < 8) ? i : inxt) * (NK * NC) + ((rr & 7) * 128) * NC;
    short* dst = buf[rr & 1];
#pragma unroll
    for (int it = 0; it < 8; ++it) {
      int n = it * 512 + t, row = n >> 5, ch = n & 31;
      gl_lds16(base + row * NC + ((ch ^ (row & 15)) << 3), dst + (size_t)n * 8);
    }
  };

  // ---- prologue: rows -> buf0, labels -> LDS ----
#pragma unroll
  for (int it = 0; it < 4; ++it) {
    int n = it * 512 + t, row = n >> 5, ch = n & 31;
    gl_lds16(SFrow + row * NC + ((ch ^ (row & 15)) << 3), buf[0] + (size_t)n * 8);
  }
  labLds[t] = sel_lab[i * NK + t];
  labLds[512 + t] = sel_lab[i * NK + 512 + t];
  labLds[1024 + t] = sel_lab[inxt * NK + t];
  labLds[1536 + t] = sel_lab[inxt * NK + 512 + t];
  ASM_VMCNT0; ASM_LGKM0; MEMFENCE; BARRIER; MEMFENCE;

  short8 afrag[2][8];
#pragma unroll
  for (int rt = 0; rt < 2; ++rt) {
    const int arow = rw * 32 + rt * 16 + lr;
#pragma unroll
    for (int ks = 0; ks < 8; ++ks) {
      int ch = ks * 4 + lg;
      afrag[rt][ks] = *(const short8*)(buf[0] + arow * 256 + ((ch ^ (arow & 15)) << 3));
    }
  }
  int rlab[2][4];
#pragma unroll
  for (int rt = 0; rt < 2; ++rt)
#pragma unroll
    for (int jj = 0; jj < 4; ++jj) {
      int L = labLds[strip * 64 + rw * 32 + rt * 16 + 4 * lg + jj];
      rlab[rt][jj] = (L == IGN) ? -1 : L;
    }
  ASM_LGKM0; SCHEDB; MEMFENCE; BARRIER; MEMFENCE;   // buf0 free

  stage_round(0);
  stage_round(1);

  ASM_VMCNT8; MEMFENCE; BARRIER; MEMFENCE;     // round 0 ready

  float SA[2][4], NPr[2][4], PEr[2][4], ETr[2][4];
  float SX[2][4], NX[2][4], PX[2][4];
#pragma unroll
  for (int rt = 0; rt < 2; ++rt)
#pragma unroll
    for (int jj = 0; jj < 4; ++jj) {
      SA[rt][jj] = 0.f; NPr[rt][jj] = 0.f; PEr[rt][jj] = 0.f; ETr[rt][jj] = 0.f;
      SX[rt][jj] = 0.f; NX[rt][jj] = 0.f; PX[rt][jj] = 0.f;
    }

  const int rs = strip >> 1;                    // diag round
  const bool dwave = ((ch4 >> 1) == (strip & 1));

  float accP[2][2][4];
  int clP[2] = {-2, -2};
  float cvfP[2] = {0.f, 0.f};
  float cSp[2], cNp[2], cEp[2];

  auto epi_self = [&](int rp) {
    const bool isdiag = (rp == rs) && dwave;
#pragma unroll
    for (int rt = 0; rt < 2; ++rt)
#pragma unroll
      for (int c2 = 0; c2 < 2; ++c2) {
        const int clc = clP[c2]; const float cvc = cvfP[c2];
        const int gc = rp * 128 + ch4 * 32 + c2 * 16 + lr;
        const int grb = strip * 64 + rw * 32 + rt * 16 + 4 * lg;
#pragma unroll
        for (int jj = 0; jj < 4; ++jj) {
          float a = accP[rt][c2][jj];
          float E = fexp2(a);
          float Ev = cvc * E;
          float pm = (rlab[rt][jj] == clc) ? 1.f : 0.f;
          if (isdiag) {
            bool ok = (grb + jj) != gc;
            pm = ok ? pm : 0.f;
            Ev = ok ? Ev : 0.f;
          }
          SA[rt][jj] += pm * a; NPr[rt][jj] += pm;
          PEr[rt][jj] += pm * Ev; ETr[rt][jj] += Ev;
        }
      }
  };

  auto epi_cross = [&]() {   // consumes accP/clP; writes cSp/cNp/cEp + colAcc
#pragma unroll
    for (int c2 = 0; c2 < 2; ++c2) { cSp[c2] = 0.f; cNp[c2] = 0.f; cEp[c2] = 0.f; }
#pragma unroll
    for (int rt = 0; rt < 2; ++rt)
#pragma unroll
      for (int c2 = 0; c2 < 2; ++c2) {
        const int clc = clP[c2];
#pragma unroll
        for (int jj = 0; jj < 4; ++jj) {
          float a = accP[rt][c2][jj];
          float E = fexp2(a);
          float pm = (rlab[rt][jj] == clc) ? 1.f : 0.f;
          float pa = pm * a, pe = pm * E;
          SX[rt][jj] += pa; NX[rt][jj] += pm; PX[rt][jj] += pe;
          cSp[c2] += pa; cNp[c2] += pm; cEp[c2] += pe;
        }
      }
#pragma unroll
    for (int c2 = 0; c2 < 2; ++c2) {
      cSp[c2] += __shfl_xor(cSp[c2], 16); cSp[c2] += __shfl_xor(cSp[c2], 32);
      cNp[c2] += __shfl_xor(cNp[c2], 16); cNp[c2] += __shfl_xor(cNp[c2], 32);
      cEp[c2] += __shfl_xor(cEp[c2], 16); cEp[c2] += __shfl_xor(cEp[c2], 32);
      if (lg == 0) colAcc[rw][ch4 * 32 + c2 * 16 + lr] = make_float4(cSp[c2], cNp[c2], cEp[c2], 0.f);
    }
  };

  auto cp_store = [&](int rp) {   // after a barrier; rp is a cross round
    if (rw == 1 && lg == 0) {
#pragma unroll
      for (int c2 = 0; c2 < 2; ++c2) {
        int col = ch4 * 32 + c2 * 16 + lr;
        float4 o = colAcc[0][col];
        Cp[(i * 16 + strip) * NK + (rp & 7) * 128 + col] =
            make_float4(cSp[c2] + o.x, cNp[c2] + o.y, (cEp[c2] + o.z) * SFAC, 0.f);
      }
    }
  };

  // ================= 16 rounds, epilogue pipelined by one =================
  for (int r = 0; r < 16; ++r) {
    int cl[2]; float cvf[2];
#pragma unroll
    for (int c2 = 0; c2 < 2; ++c2) {
      int L = labLds[((r < 8) ? 0 : 1024) + (r & 7) * 128 + ch4 * 32 + c2 * 16 + lr];
      cl[c2] = (L == IGN) ? -2 : L;
      cvf[c2] = (L == IGN) ? 0.f : 1.f;
    }

    const short* bb = buf[r & 1];
    f32x4 acc[2][2];
#pragma unroll
    for (int rt = 0; rt < 2; ++rt)
#pragma unroll
      for (int c2 = 0; c2 < 2; ++c2) acc[rt][c2] = f32x4{0.f, 0.f, 0.f, 0.f};
#pragma unroll
    for (int ks = 0; ks < 8; ++ks) {
      int ch = ks * 4 + lg;
      short8 b0, b1;
      {
        int br0 = ch4 * 32 + lr, br1 = ch4 * 32 + 16 + lr;
        b0 = *(const short8*)(bb + br0 * 256 + ((ch ^ (br0 & 15)) << 3));
        b1 = *(const short8*)(bb + br1 * 256 + ((ch ^ (br1 & 15)) << 3));
      }
      acc[0][0] = __builtin_amdgcn_mfma_f32_16x16x32_bf16(afrag[0][ks], b0, acc[0][0], 0, 0, 0);
      acc[0][1] = __builtin_amdgcn_mfma_f32_16x16x32_bf16(afrag[0][ks], b1, acc[0][1], 0, 0, 0);
      acc[1][0] = __builtin_amdgcn_mfma_f32_16x16x32_bf16(afrag[1][ks], b0, acc[1][0], 0, 0, 0);
      acc[1][1] = __builtin_amdgcn_mfma_f32_16x16x32_bf16(afrag[1][ks], b1, acc[1][1], 0, 0, 0);
    }

    // ---- deferred epilogue for round r-1 (independent of acc(r)) ----
    if (r >= 1) {
      if (r <= 8) epi_self(r - 1);
      else        epi_cross();
    }

    // ---- save this round's state for its (deferred) epilogue ----
#pragma unroll
    for (int rt = 0; rt < 2; ++rt)
#pragma unroll
      for (int c2 = 0; c2 < 2; ++c2)
#pragma unroll
        for (int jj = 0; jj < 4; ++jj) accP[rt][c2][jj] = acc[rt][c2][jj];
    clP[0] = cl[0]; clP[1] = cl[1];
    cvfP[0] = cvf[0]; cvfP[1] = cvf[1];

    ASM_LGKM0; SCHEDB;
    MEMFENCE; BARRIER; MEMFENCE;               // barrier1: buf[r&1] free, colAcc visible
    if (r >= 9) cp_store(r - 1);
    if (r < 14)      { stage_round(r + 2); ASM_VMCNT8; }
    else if (r == 14) { ASM_VMCNT0; }
    MEMFENCE; BARRIER; MEMFENCE;               // barrier2
  }

  // ---- drain: epilogue + Cp store for round 15 ----
  epi_cross();
  ASM_LGKM0; SCHEDB; MEMFENCE; BARRIER; MEMFENCE;
  cp_store(15);

  // ---- self fold -> rredS, cross fold -> rredX ----
#pragma unroll
  for (int rt = 0; rt < 2; ++rt)
#pragma unroll
    for (int jj = 0; jj < 4; ++jj) {
      float a = SA[rt][jj], b4 = NPr[rt][jj], c4 = PEr[rt][jj], d4 = ETr[rt][jj];
      float x = SX[rt][jj], y4 = NX[rt][jj], z4 = PX[rt][jj];
#pragma unroll
      for (int m = 1; m <= 8; m <<= 1) {
        a += __shfl_xor(a, m); b4 += __shfl_xor(b4, m);
        c4 += __shfl_xor(c4, m); d4 += __shfl_xor(d4, m);
        x += __shfl_xor(x, m); y4 += __shfl_xor(y4, m); z4 += __shfl_xor(z4, m);
      }
      if (lr == 0) {
        rredS[ch4][rw * 32 + rt * 16 + 4 * lg + jj] = make_float4(a, b4, c4, d4);
        rredX[ch4][rw * 32 + rt * 16 + 4 * lg + jj] = make_float4(x, y4, z4, 0.f);
      }
    }
  __syncthreads();

  // ---- per-row pass: SNd/Rii writes + local a1 ----
  if (t < 64) {
    float4 sS = rredS[0][t], sX = rredX[0][t];
#pragma unroll
    for (int c4 = 1; c4 < 4; ++c4) {
      float4 u = rredS[c4][t], v = rredX[c4][t];
      sS.x += u.x; sS.y += u.y; sS.z += u.z; sS.w += u.w;
      sX.x += v.x; sX.y += v.y; sX.z += v.z;
    }
    float SNL = sS.w - sS.z;
    float SN = SNL * SFAC + 1e-8f;
    float LSN = __logf(SN), rSN = 1.f / SN;
    int g = i * NK + strip * 64 + t;
    SNd[g] = make_float2(LSN, rSN);
    Rii[g] = make_float4(sS.x, sS.y, sS.z * SFAC, 0.f);
    float pps = LN2 * (sS.x - CBIAS * sS.y) - sS.y * LSN - rSN * (sS.z * SFAC);
    float ppx = LN2 * (sX.x - CBIAS * sX.y) - sX.y * LSN - rSN * (sX.z * SFAC);
    float np1 = sS.y + sX.y;
    float an = 0.f, ac = 0.f;
    if (np1 > 0.f) { an = -(pps + ppx) / np1; ac = 1.f; }
#pragma unroll
    for (int m = 1; m <= 32; m <<= 1) { an += __shfl_xor(an, m); ac += __shfl_xor(ac, m); }
    if (t == 0) A1arr[i * 16 + strip] = make_float2(an, ac);
  }
  __syncthreads();

  // ---- counter dance ----
  if (t == 0) {
    __threadfence();
    int o1 = atomicAdd(&cnt[i], 1);
    int o2 = atomicAdd(&cnt[iprev], 1);
    fA = (o1 == 31); fB = (o2 == 31);
  }
  __syncthreads();

  auto pair_fold = [&](int p) {
    const int q = (p + 1) & 15;
    ACQ_AGENT;
    float an = 0.f, ac = 0.f;
    for (int r2 = t; r2 < NK; r2 += 512) {
      float4 rii = Rii[q * NK + r2];
      float2 sn = SNd[q * NK + r2];
      float cs = 0.f, cn = 0.f, ce = 0.f;
#pragma unroll
      for (int s2 = 0; s2 < 16; ++s2) {
        float4 c = Cp[(p * 16 + s2) * NK + r2];
        cs += c.x; cn += c.y; ce += c.z;
      }
      float ppc = LN2 * (cs - CBIAS * cn) - cn * sn.x - sn.y * ce;
      float ppi = LN2 * (rii.x - CBIAS * rii.y) - rii.y * sn.x - sn.y * rii.z;
      float np2 = rii.y + cn;
      if (np2 > 0.f) { an -= (ppi + ppc) / np2; ac += 1.f; }
    }
#pragma unroll
    for (int m = 1; m <= 32; m <<= 1) { an += __shfl_xor(an, m); ac += __shfl_xor(ac, m); }
    if (lane == 0) fold2[w] = make_float2(an, ac);
    __syncthreads();
    if (t == 0) {
      float a2n = 0.f, a2c = 0.f;
#pragma unroll
      for (int k2 = 0; k2 < 8; ++k2) { a2n += fold2[k2].x; a2c += fold2[k2].y; }
      float a1n = 0.f, a1c = 0.f;
#pragma unroll
      for (int s2 = 0; s2 < 16; ++s2) {
        float2 a = A1arr[q * 16 + s2];
        a1n += a.x; a1c += a.y;
      }
      Aimg[q] = make_float2(a1n + a2n, a1c + a2c);
      __threadfence();
      int f = atomicAdd(findone, 1);
      if (f == NB - 1) {
        ACQ_AGENT;
        float v = 0.f;
#pragma unroll
        for (int im = 0; im < NB; ++im) {
          float2 gg = Aimg[im];
          v += gg.x / fmaxf(gg.y, 1.f);
        }
        out[0] = v / (float)NB;
      }
    }
    __syncthreads();
  };

  if (fA) pair_fold(i);
  if (fB) pair_fold(iprev);
}

}  // namespace

extern "C" void kernel_launch(void* const* d_in, const int* in_sizes, int n_in,
                              void* d_out, int out_size, void* d_ws, size_t ws_size,
                              hipStream_t stream) {
  (void)in_sizes; (void)n_in; (void)out_size; (void)ws_size;
  const float* feats  = (const float*)d_in[0];
  const int*   labels = (const int*)d_in[1];
  float* out = (float*)d_out;
  char* ws = (char*)d_ws;

  int* sel_lab = (int*)ws;                                       // 64 KB
  int* sel_idx = (int*)(ws + (64 << 10));                        // 64 KB
  unsigned short* SF = (unsigned short*)(ws + (128 << 10));      // 8 MB
  size_t off = (128 << 10) + (size_t)NB * NK * NC * 2;
  float2* SNd = (float2*)(ws + off);  off += (size_t)NB * NK * 8;       // 128 KB
  float4* Rii = (float4*)(ws + off);  off += (size_t)NB * NK * 16;      // 256 KB
  float4* Cp  = (float4*)(ws + off);  off += (size_t)NB * 16 * NK * 16; // 4 MB
  float2* A1arr = (float2*)(ws + off); off += (size_t)NB * 16 * 8;
  float2* Aimg = (float2*)(ws + off);  off += NB * 8;
  int* cnt = (int*)(ws + off);         off += 16 * 4;
  int* findone = (int*)(ws + off);

  pcl_sample<<<NB, 1024, 0, stream>>>(labels, sel_lab, sel_idx, cnt, findone);
  pcl_gather<<<256, 1024, 0, stream>>>(feats, sel_lab, sel_idx, SF);
  pcl_tiles<<<256, 512, 0, stream>>>(SF, sel_lab, SNd, Rii, Cp,
                                     A1arr, Aimg, cnt, findone, out);
}

// Round 17
// 112.624 us; speedup vs baseline: 1.5912x; 1.5854x over previous
//
#include <hip/hip_runtime.h>
#include <hip/hip_bf16.h>

namespace {

constexpr int NB  = 16;
constexpr int NC  = 256;
constexpr int NHW = 16384;
constexpr int NK  = 1024;
constexpr int IGN = 255;
constexpr float SCALE = 4.5398164f;   // sqrt((1/0.07) * log2(e))
constexpr float CBIAS = 20.609929f;   // (1/0.07) * log2(e)
constexpr float LN2   = 0.69314718f;

typedef __attribute__((ext_vector_type(8))) short short8;
typedef __attribute__((ext_vector_type(4))) float f32x4;
typedef unsigned int u32;

#define ASM_VMCNT8 asm volatile("s_waitcnt vmcnt(8)" ::: "memory")
#define ASM_VMCNT0 asm volatile("s_waitcnt vmcnt(0)" ::: "memory")
#define ASM_LGKM0  asm volatile("s_waitcnt lgkmcnt(0)" ::: "memory")
#define SCHEDB     __builtin_amdgcn_sched_barrier(0)
#define MEMFENCE   asm volatile("" ::: "memory")
#define BARRIER    __builtin_amdgcn_s_barrier()
#define ACQ_AGENT  __builtin_amdgcn_fence(__ATOMIC_ACQUIRE, "agent")

__device__ __forceinline__ float fexp2(float x) { return __builtin_exp2f(x); }

__device__ __forceinline__ void gl_lds16(const void* g, void* l) {
  __builtin_amdgcn_global_load_lds((const __attribute__((address_space(1))) u32*)g,
                                   (__attribute__((address_space(3))) u32*)l, 16, 0, 0);
}

// ---------------------------------------------------------------- kernel 1
__global__ __launch_bounds__(1024) void pcl_sample(const int* __restrict__ labels,
                                                   int* __restrict__ sel_lab,
                                                   int* __restrict__ sel_idx,
                                                   int* __restrict__ cnt,
                                                   int* __restrict__ findone) {
  const int b = blockIdx.x, t = threadIdx.x, lane = t & 63, w = t >> 6;  // 16 waves
  if (t == 0) { cnt[b] = 0; if (b == 0) *findone = 0; }
  __shared__ int labL[1024 * 17];     // 68 KB
  __shared__ int wtot[16];

  sel_lab[b * NK + t] = IGN;

  const int* lab = labels + b * NHW;
#pragma unroll
  for (int k = 0; k < 16; ++k) {
    int idx = k * 1024 + t;
    labL[(idx >> 4) * 17 + (idx & 15)] = lab[idx];
  }
  __syncthreads();

  int cfg = 0, cbg = 0;
#pragma unroll
  for (int i = 0; i < 16; ++i) {
    int L = labL[t * 17 + i];
    cfg += (L != IGN && L != 0);
    cbg += (L == 0);
  }
  int packed = cfg | (cbg << 15);
  int incl = packed;
#pragma unroll
  for (int off = 1; off < 64; off <<= 1) {
    int n = __shfl_up(incl, off);
    if (lane >= off) incl += n;
  }
  if (lane == 63) wtot[w] = incl;
  __syncthreads();
  int wb = 0, total = 0;
#pragma unroll
  for (int ww = 0; ww < 16; ++ww) { int v = wtot[ww]; total += v; if (ww < w) wb += v; }
  int excl = incl - packed + wb;
  int rf  = excl & 32767;
  int rbg = (excl >> 15) & 32767;
  const int nfg = total & 32767;
  if (rf < NK || nfg + rbg < NK) {
#pragma unroll
    for (int i = 0; i < 16; ++i) {
      int L = labL[t * 17 + i];
      if (L == IGN) continue;
      if (L != 0) {
        if (rf < NK) { sel_lab[b * NK + rf] = L; sel_idx[b * NK + rf] = t * 16 + i; }
        ++rf;
      } else {
        int s = nfg + rbg;
        if (s < NK) { sel_lab[b * NK + s] = L; sel_idx[b * NK + s] = t * 16 + i; }
        ++rbg;
      }
    }
  }
}

// ---------------------------------------------------------------- kernel 2
__global__ __launch_bounds__(1024) void pcl_gather(const float* __restrict__ feats,
                                                   const int* __restrict__ sel_lab,
                                                   const int* __restrict__ sel_idx,
                                                   unsigned short* __restrict__ SF) {
  const int b = blockIdx.x >> 4, kb = blockIdx.x & 15;
  const int t = threadIdx.x, s = t & 63, w = t >> 6;
  __shared__ float fbuf[64][257];
  __shared__ float sqs[16][64];
  __shared__ float rn[64];
  const int gk = b * NK + kb * 64 + s;
  const int lb = sel_lab[gk];
  const int p = (lb != IGN) ? sel_idx[gk] : -1;
  const float* fb = feats + (size_t)b * NC * NHW;
  float sq = 0.f;
#pragma unroll
  for (int cc = 0; cc < 16; ++cc) {
    int c = w * 16 + cc;
    float v = (p >= 0) ? fb[(size_t)c * NHW + p] : 0.f;
    fbuf[s][c] = v;
    sq += v * v;
  }
  sqs[w][s] = sq;
  __syncthreads();
  if (t < 64) {
    float tot = 0.f;
#pragma unroll
    for (int k2 = 0; k2 < 16; ++k2) tot += sqs[k2][t];
    rn[t] = SCALE / fmaxf(sqrtf(tot), 1e-12f);
  }
  __syncthreads();
#pragma unroll
  for (int it = 0; it < 2; ++it) {
    int slot = it * 1024 + t;
    int ss = slot >> 5, ch = slot & 31;
    float r = rn[ss];
    short8 v8;
#pragma unroll
    for (int e = 0; e < 8; ++e) {
      float x = fbuf[ss][ch * 8 + e] * r;
      __hip_bfloat16 h = __float2bfloat16(x);
      unsigned short u; __builtin_memcpy(&u, &h, 2);
      v8[e] = (short)u;
    }
    *(short8*)(SF + ((size_t)(b * NK + kb * 64 + ss)) * NC + ch * 8) = v8;
  }
}

// ---------------------------------------------------------------- kernel 3
// BARRIER-FREE main loop. 8 waves = (rw 0..1: 32-row half) x (cg 0..3).
// cg 0,1: self cols (image i, 512-col half); cg 2,3: cross cols (image i+1).
// Each wave owns a PRIVATE 2x8KB LDS double-buffer and walks its 512 cols in
// 32 chunks of 16, fully self-paced with per-wave counted vmcnt — no
// lockstep, so the 2 waves/SIMD cover each other's stalls. Cross col sums
// stored as per-rw partials (Cp2), summed in pair_fold. Register budget
// ~120 (afrag 64 + acc 8 + stats 32 + temps) fits the observed 128 cap.
__global__ __launch_bounds__(512) void pcl_tiles(
    const unsigned short* __restrict__ SF, const int* __restrict__ sel_lab,
    float2* __restrict__ SNd, float4* __restrict__ Rii, float4* __restrict__ Cp2,
    float2* __restrict__ A1arr, float2* __restrict__ Aimg,
    int* __restrict__ cnt, int* __restrict__ findone, float* __restrict__ out) {
  const int id = blockIdx.x;
  const int i = id & 15, strip = id >> 4;
  const int inxt = (i + 1) & 15, iprev = (i + 15) & 15;
  const int t = threadIdx.x, lane = t & 63, w = t >> 6;
  const int rw = w & 1, cg = w >> 1;
  const bool selfw = (cg < 2);
  const int colbase = (cg & 1) * 512;
  const int lg = lane >> 4, lr = lane & 15;
  const float SFAC = __builtin_exp2f(-CBIAS);

  __shared__ short buf[8][2][4096];            // 8 waves x 2 x 8KB = 128 KB
  __shared__ int labLds[2048];                 // 8 KB
  __shared__ float4 rredS[2][64];              // 2 KB
  __shared__ float4 rredX[2][64];              // 2 KB
  __shared__ float2 fold2[8];
  __shared__ int fA, fB;

  // ---- prologue: 64 rows -> first 32KB of buf (shared), labels -> LDS ----
  {
    short* rowbuf = &buf[0][0][0];
    const unsigned short* SFrow = SF + (size_t)i * (NK * NC) + strip * 64 * NC;
#pragma unroll
    for (int it = 0; it < 4; ++it) {
      int n = it * 512 + t, row = n >> 5, ch = n & 31;
      gl_lds16(SFrow + row * NC + ((ch ^ (row & 15)) << 3), rowbuf + (size_t)n * 8);
    }
    labLds[t] = sel_lab[i * NK + t];
    labLds[512 + t] = sel_lab[i * NK + 512 + t];
    labLds[1024 + t] = sel_lab[inxt * NK + t];
    labLds[1536 + t] = sel_lab[inxt * NK + 512 + t];
    ASM_VMCNT0; ASM_LGKM0; MEMFENCE; BARRIER; MEMFENCE;
  }

  short8 afrag[2][8];
  {
    const short* rowbuf = &buf[0][0][0];
#pragma unroll
    for (int rt = 0; rt < 2; ++rt) {
      const int arow = rw * 32 + rt * 16 + lr;
#pragma unroll
      for (int ks = 0; ks < 8; ++ks) {
        int ch = ks * 4 + lg;
        afrag[rt][ks] = *(const short8*)(rowbuf + arow * 256 + ((ch ^ (arow & 15)) << 3));
      }
    }
  }
  int rlab[2][4];
#pragma unroll
  for (int rt = 0; rt < 2; ++rt)
#pragma unroll
    for (int jj = 0; jj < 4; ++jj) {
      int L = labLds[strip * 64 + rw * 32 + rt * 16 + 4 * lg + jj];
      rlab[rt][jj] = (L == IGN) ? -1 : L;
    }
  ASM_LGKM0; SCHEDB; MEMFENCE; BARRIER; MEMFENCE;   // row region free

  const unsigned short* SFc = SF + (size_t)(selfw ? i : inxt) * (NK * NC);
  const int labBase = selfw ? 0 : 1024;
  short* wb[2] = { &buf[w][0][0], &buf[w][1][0] };

  auto stage_chunk = [&](int c) {      // wave-private: 16 cols x 256 ch
    short* dst = wb[c & 1];
    const unsigned short* base = SFc + (size_t)(colbase + c * 16) * NC;
#pragma unroll
    for (int it2 = 0; it2 < 8; ++it2) {
      int n = it2 * 64 + lane, row16 = n >> 5, ch = n & 31;
      gl_lds16(base + row16 * NC + ((ch ^ row16) << 3), dst + (size_t)n * 8);
    }
  };

  stage_chunk(0);
  stage_chunk(1);

  float S1[2][4], N1[2][4], P1[2][4], ET[2][4];
#pragma unroll
  for (int rt = 0; rt < 2; ++rt)
#pragma unroll
    for (int jj = 0; jj < 4; ++jj) { S1[rt][jj] = 0.f; N1[rt][jj] = 0.f; P1[rt][jj] = 0.f; ET[rt][jj] = 0.f; }

  // ================= 32 chunks, barrier-free =================
  for (int c = 0; c < 32; ++c) {
    if (c < 31) { ASM_VMCNT8; } else { ASM_VMCNT0; }
    MEMFENCE;

    int L = labLds[labBase + colbase + c * 16 + lr];
    const int clc = (L == IGN) ? -2 : L;
    const float cvc = (L == IGN) ? 0.f : 1.f;

    const short* bb = wb[c & 1];
    f32x4 acc[2];
    acc[0] = f32x4{0.f, 0.f, 0.f, 0.f};
    acc[1] = f32x4{0.f, 0.f, 0.f, 0.f};
#pragma unroll
    for (int ks = 0; ks < 8; ++ks) {
      int ch = ks * 4 + lg;
      short8 bf = *(const short8*)(bb + lr * 256 + ((ch ^ lr) << 3));
      acc[0] = __builtin_amdgcn_mfma_f32_16x16x32_bf16(afrag[0][ks], bf, acc[0], 0, 0, 0);
      acc[1] = __builtin_amdgcn_mfma_f32_16x16x32_bf16(afrag[1][ks], bf, acc[1], 0, 0, 0);
    }

    const bool isdiag = selfw && (((colbase + c * 16) >> 6) == strip);
    float csS = 0.f, csN = 0.f, csE = 0.f;
#pragma unroll
    for (int rt = 0; rt < 2; ++rt) {
      const int grb = strip * 64 + rw * 32 + rt * 16 + 4 * lg;
#pragma unroll
      for (int jj = 0; jj < 4; ++jj) {
        float a = acc[rt][jj];
        float E = fexp2(a);
        float Ev = cvc * E;
        float pm = (rlab[rt][jj] == clc) ? 1.f : 0.f;
        if (isdiag) {
          bool ok = (grb + jj) != (colbase + c * 16 + lr);
          pm = ok ? pm : 0.f;
          Ev = ok ? Ev : 0.f;
        }
        S1[rt][jj] += pm * a; N1[rt][jj] += pm; P1[rt][jj] += pm * Ev;
        if (selfw) ET[rt][jj] += Ev;
        else { csS += pm * a; csN += pm; csE += pm * Ev; }
      }
    }

    if (!selfw) {                       // per-chunk col sums over this wave's 32 rows
      csS += __shfl_xor(csS, 16); csS += __shfl_xor(csS, 32);
      csN += __shfl_xor(csN, 16); csN += __shfl_xor(csN, 32);
      csE += __shfl_xor(csE, 16); csE += __shfl_xor(csE, 32);
      if (lg == 0)
        Cp2[((size_t)(i * 16 + strip) * 2 + rw) * NK + colbase + c * 16 + lr] =
            make_float4(csS, csN, csE * SFAC, 0.f);
    }

    ASM_LGKM0; SCHEDB;                  // chunk c's ds_reads fully consumed
    if (c < 30) stage_chunk(c + 2);
  }

  // ---- fold row stats -> rredS / rredX ----
#pragma unroll
  for (int rt = 0; rt < 2; ++rt)
#pragma unroll
    for (int jj = 0; jj < 4; ++jj) {
      float a = S1[rt][jj], b4 = N1[rt][jj], c4 = P1[rt][jj], d4 = ET[rt][jj];
#pragma unroll
      for (int m = 1; m <= 8; m <<= 1) {
        a += __shfl_xor(a, m); b4 += __shfl_xor(b4, m);
        c4 += __shfl_xor(c4, m); d4 += __shfl_xor(d4, m);
      }
      if (lr == 0) {
        int row = rw * 32 + rt * 16 + 4 * lg + jj;
        if (selfw) rredS[cg][row] = make_float4(a, b4, c4, d4);
        else       rredX[cg - 2][row] = make_float4(a, b4, c4, 0.f);
      }
    }
  __syncthreads();

  // ---- per-row pass: SNd/Rii writes + local a1 ----
  if (t < 64) {
    float4 s0 = rredS[0][t], s1 = rredS[1][t];
    float4 x0 = rredX[0][t], x1 = rredX[1][t];
    float4 sS = make_float4(s0.x + s1.x, s0.y + s1.y, s0.z + s1.z, s0.w + s1.w);
    float4 sX = make_float4(x0.x + x1.x, x0.y + x1.y, x0.z + x1.z, 0.f);
    float SNL = sS.w - sS.z;
    float SN = SNL * SFAC + 1e-8f;
    float LSN = __logf(SN), rSN = 1.f / SN;
    int g = i * NK + strip * 64 + t;
    SNd[g] = make_float2(LSN, rSN);
    Rii[g] = make_float4(sS.x, sS.y, sS.z * SFAC, 0.f);
    float pps = LN2 * (sS.x - CBIAS * sS.y) - sS.y * LSN - rSN * (sS.z * SFAC);
    float ppx = LN2 * (sX.x - CBIAS * sX.y) - sX.y * LSN - rSN * (sX.z * SFAC);
    float np1 = sS.y + sX.y;
    float an = 0.f, ac = 0.f;
    if (np1 > 0.f) { an = -(pps + ppx) / np1; ac = 1.f; }
#pragma unroll
    for (int m = 1; m <= 32; m <<= 1) { an += __shfl_xor(an, m); ac += __shfl_xor(ac, m); }
    if (t == 0) A1arr[i * 16 + strip] = make_float2(an, ac);
  }
  __syncthreads();

  // ---- counter dance ----
  if (t == 0) {
    __threadfence();
    int o1 = atomicAdd(&cnt[i], 1);
    int o2 = atomicAdd(&cnt[iprev], 1);
    fA = (o1 == 31); fB = (o2 == 31);
  }
  __syncthreads();

  auto pair_fold = [&](int p) {
    const int q = (p + 1) & 15;
    ACQ_AGENT;
    float an = 0.f, ac = 0.f;
    for (int r2 = t; r2 < NK; r2 += 512) {
      float4 rii = Rii[q * NK + r2];
      float2 sn = SNd[q * NK + r2];
      float cs = 0.f, cn = 0.f, ce = 0.f;
#pragma unroll
      for (int s2 = 0; s2 < 16; ++s2) {
#pragma unroll
        for (int h = 0; h < 2; ++h) {
          float4 c = Cp2[((size_t)(p * 16 + s2) * 2 + h) * NK + r2];
          cs += c.x; cn += c.y; ce += c.z;
        }
      }
      float ppc = LN2 * (cs - CBIAS * cn) - cn * sn.x - sn.y * ce;
      float ppi = LN2 * (rii.x - CBIAS * rii.y) - rii.y * sn.x - sn.y * rii.z;
      float np2 = rii.y + cn;
      if (np2 > 0.f) { an -= (ppi + ppc) / np2; ac += 1.f; }
    }
#pragma unroll
    for (int m = 1; m <= 32; m <<= 1) { an += __shfl_xor(an, m); ac += __shfl_xor(ac, m); }
    if (lane == 0) fold2[w] = make_float2(an, ac);
    __syncthreads();
    if (t == 0) {
      float a2n = 0.f, a2c = 0.f;
#pragma unroll
      for (int k2 = 0; k2 < 8; ++k2) { a2n += fold2[k2].x; a2c += fold2[k2].y; }
      float a1n = 0.f, a1c = 0.f;
#pragma unroll
      for (int s2 = 0; s2 < 16; ++s2) {
        float2 a = A1arr[q * 16 + s2];
        a1n += a.x; a1c += a.y;
      }
      Aimg[q] = make_float2(a1n + a2n, a1c + a2c);
      __threadfence();
      int f = atomicAdd(findone, 1);
      if (f == NB - 1) {
        ACQ_AGENT;
        float v = 0.f;
#pragma unroll
        for (int im = 0; im < NB; ++im) {
          float2 gg = Aimg[im];
          v += gg.x / fmaxf(gg.y, 1.f);
        }
        out[0] = v / (float)NB;
      }
    }
    __syncthreads();
  };

  if (fA) pair_fold(i);
  if (fB) pair_fold(iprev);
}

}  // namespace

extern "C" void kernel_launch(void* const* d_in, const int* in_sizes, int n_in,
                              void* d_out, int out_size, void* d_ws, size_t ws_size,
                              hipStream_t stream) {
  (void)in_sizes; (void)n_in; (void)out_size; (void)ws_size;
  const float* feats  = (const float*)d_in[0];
  const int*   labels = (const int*)d_in[1];
  float* out = (float*)d_out;
  char* ws = (char*)d_ws;

  int* sel_lab = (int*)ws;                                       // 64 KB
  int* sel_idx = (int*)(ws + (64 << 10));                        // 64 KB
  unsigned short* SF = (unsigned short*)(ws + (128 << 10));      // 8 MB
  size_t off = (128 << 10) + (size_t)NB * NK * NC * 2;
  float2* SNd = (float2*)(ws + off);  off += (size_t)NB * NK * 8;           // 128 KB
  float4* Rii = (float4*)(ws + off);  off += (size_t)NB * NK * 16;          // 256 KB
  float4* Cp2 = (float4*)(ws + off);  off += (size_t)NB * 16 * 2 * NK * 16; // 8 MB
  float2* A1arr = (float2*)(ws + off); off += (size_t)NB * 16 * 8;
  float2* Aimg = (float2*)(ws + off);  off += NB * 8;
  int* cnt = (int*)(ws + off);         off += 16 * 4;
  int* findone = (int*)(ws + off);

  pcl_sample<<<NB, 1024, 0, stream>>>(labels, sel_lab, sel_idx, cnt, findone);
  pcl_gather<<<256, 1024, 0, stream>>>(feats, sel_lab, sel_idx, SF);
  pcl_tiles<<<256, 512, 0, stream>>>(SF, sel_lab, SNd, Rii, Cp2,
                                     A1arr, Aimg, cnt, findone, out);
}

// Round 18
// 86.532 us; speedup vs baseline: 2.0710x; 1.3015x over previous
//
#include <hip/hip_runtime.h>
#include <hip/hip_bf16.h>

namespace {

constexpr int NB  = 16;
constexpr int NC  = 256;
constexpr int NHW = 16384;
constexpr int NK  = 1024;
constexpr int IGN = 255;
constexpr float SCALE = 4.5398164f;   // sqrt((1/0.07) * log2(e))
constexpr float CBIAS = 20.609929f;   // (1/0.07) * log2(e)
constexpr float LN2   = 0.69314718f;

typedef __attribute__((ext_vector_type(8))) short short8;
typedef __attribute__((ext_vector_type(4))) float f32x4;
typedef unsigned int u32;

#define ASM_VMCNT8 asm volatile("s_waitcnt vmcnt(8)" ::: "memory")
#define ASM_VMCNT0 asm volatile("s_waitcnt vmcnt(0)" ::: "memory")
#define ASM_LGKM0  asm volatile("s_waitcnt lgkmcnt(0)" ::: "memory")
#define SCHEDB     __builtin_amdgcn_sched_barrier(0)
#define MEMFENCE   asm volatile("" ::: "memory")
#define BARRIER    __builtin_amdgcn_s_barrier()
#define ACQ_AGENT  __builtin_amdgcn_fence(__ATOMIC_ACQUIRE, "agent")

__device__ __forceinline__ float fexp2(float x) { return __builtin_exp2f(x); }

__device__ __forceinline__ void gl_lds16(const void* g, void* l) {
  __builtin_amdgcn_global_load_lds((const __attribute__((address_space(1))) u32*)g,
                                   (__attribute__((address_space(3))) u32*)l, 16, 0, 0);
}

// ---------------------------------------------------------------- kernel 1
__global__ __launch_bounds__(1024) void pcl_sample(const int* __restrict__ labels,
                                                   int* __restrict__ sel_lab,
                                                   int* __restrict__ sel_idx,
                                                   int* __restrict__ cnt,
                                                   int* __restrict__ findone) {
  const int b = blockIdx.x, t = threadIdx.x, lane = t & 63, w = t >> 6;  // 16 waves
  if (t == 0) { cnt[b] = 0; if (b == 0) *findone = 0; }
  __shared__ int labL[1024 * 17];     // 68 KB
  __shared__ int wtot[16];

  sel_lab[b * NK + t] = IGN;

  const int* lab = labels + b * NHW;
#pragma unroll
  for (int k = 0; k < 16; ++k) {
    int idx = k * 1024 + t;
    labL[(idx >> 4) * 17 + (idx & 15)] = lab[idx];
  }
  __syncthreads();

  int cfg = 0, cbg = 0;
#pragma unroll
  for (int i = 0; i < 16; ++i) {
    int L = labL[t * 17 + i];
    cfg += (L != IGN && L != 0);
    cbg += (L == 0);
  }
  int packed = cfg | (cbg << 15);
  int incl = packed;
#pragma unroll
  for (int off = 1; off < 64; off <<= 1) {
    int n = __shfl_up(incl, off);
    if (lane >= off) incl += n;
  }
  if (lane == 63) wtot[w] = incl;
  __syncthreads();
  int wb = 0, total = 0;
#pragma unroll
  for (int ww = 0; ww < 16; ++ww) { int v = wtot[ww]; total += v; if (ww < w) wb += v; }
  int excl = incl - packed + wb;
  int rf  = excl & 32767;
  int rbg = (excl >> 15) & 32767;
  const int nfg = total & 32767;
  if (rf < NK || nfg + rbg < NK) {
#pragma unroll
    for (int i = 0; i < 16; ++i) {
      int L = labL[t * 17 + i];
      if (L == IGN) continue;
      if (L != 0) {
        if (rf < NK) { sel_lab[b * NK + rf] = L; sel_idx[b * NK + rf] = t * 16 + i; }
        ++rf;
      } else {
        int s = nfg + rbg;
        if (s < NK) { sel_lab[b * NK + s] = L; sel_idx[b * NK + s] = t * 16 + i; }
        ++rbg;
      }
    }
  }
}

// ---------------------------------------------------------------- kernel 2
__global__ __launch_bounds__(1024) void pcl_gather(const float* __restrict__ feats,
                                                   const int* __restrict__ sel_lab,
                                                   const int* __restrict__ sel_idx,
                                                   unsigned short* __restrict__ SF) {
  const int b = blockIdx.x >> 4, kb = blockIdx.x & 15;
  const int t = threadIdx.x, s = t & 63, w = t >> 6;
  __shared__ float fbuf[64][257];
  __shared__ float sqs[16][64];
  __shared__ float rn[64];
  const int gk = b * NK + kb * 64 + s;
  const int lb = sel_lab[gk];
  const int p = (lb != IGN) ? sel_idx[gk] : -1;
  const float* fb = feats + (size_t)b * NC * NHW;
  float sq = 0.f;
#pragma unroll
  for (int cc = 0; cc < 16; ++cc) {
    int c = w * 16 + cc;
    float v = (p >= 0) ? fb[(size_t)c * NHW + p] : 0.f;
    fbuf[s][c] = v;
    sq += v * v;
  }
  sqs[w][s] = sq;
  __syncthreads();
  if (t < 64) {
    float tot = 0.f;
#pragma unroll
    for (int k2 = 0; k2 < 16; ++k2) tot += sqs[k2][t];
    rn[t] = SCALE / fmaxf(sqrtf(tot), 1e-12f);
  }
  __syncthreads();
#pragma unroll
  for (int it = 0; it < 2; ++it) {
    int slot = it * 1024 + t;
    int ss = slot >> 5, ch = slot & 31;
    float r = rn[ss];
    short8 v8;
#pragma unroll
    for (int e = 0; e < 8; ++e) {
      float x = fbuf[ss][ch * 8 + e] * r;
      __hip_bfloat16 h = __float2bfloat16(x);
      unsigned short u; __builtin_memcpy(&u, &h, 2);
      v8[e] = (short)u;
    }
    *(short8*)(SF + ((size_t)(b * NK + kb * 64 + ss)) * NC + ch * 8) = v8;
  }
}

// ---------------------------------------------------------------- kernel 3
// Champion (R13): 8 waves, 128-col rounds, 2-barrier cadence, depth-2
// prefetch, counted vmcnt(8), labels-in-LDS, exp2-rebased epilogue.
__global__ __launch_bounds__(512) void pcl_tiles(
    const unsigned short* __restrict__ SF, const int* __restrict__ sel_lab,
    float2* __restrict__ SNd, float4* __restrict__ Rii, float4* __restrict__ Cp,
    float2* __restrict__ A1arr, float2* __restrict__ Aimg,
    int* __restrict__ cnt, int* __restrict__ findone, float* __restrict__ out) {
  const int id = blockIdx.x;
  const int i = id & 15, strip = id >> 4;
  const int inxt = (i + 1) & 15, iprev = (i + 15) & 15;
  const int t = threadIdx.x, lane = t & 63, w = t >> 6;
  const int rw = w & 1, ch4 = w >> 1;
  const int lg = lane >> 4, lr = lane & 15;
  const float SFAC = __builtin_exp2f(-CBIAS);

  __shared__ short buf[2][128 * 256];          // 128 KB
  __shared__ int labLds[2048];                 // 8 KB
  __shared__ float4 colAcc[2][128];            // 4 KB
  __shared__ float4 rredS[4][64];              // 4 KB
  __shared__ float4 rredX[4][64];              // 4 KB
  __shared__ float2 fold2[8];
  __shared__ int fA, fB;

  const unsigned short* SFrow = SF + (size_t)i * (NK * NC) + strip * 64 * NC;

  auto stage_round = [&](int rr) {
    const unsigned short* base =
        SF + (size_t)((rr < 8) ? i : inxt) * (NK * NC) + ((rr & 7) * 128) * NC;
    short* dst = buf[rr & 1];
#pragma unroll
    for (int it = 0; it < 8; ++it) {
      int n = it * 512 + t, row = n >> 5, ch = n & 31;
      gl_lds16(base + row * NC + ((ch ^ (row & 15)) << 3), dst + (size_t)n * 8);
    }
  };

  // ---- prologue: rows -> buf0, labels -> LDS ----
#pragma unroll
  for (int it = 0; it < 4; ++it) {
    int n = it * 512 + t, row = n >> 5, ch = n & 31;
    gl_lds16(SFrow + row * NC + ((ch ^ (row & 15)) << 3), buf[0] + (size_t)n * 8);
  }
  labLds[t] = sel_lab[i * NK + t];
  labLds[512 + t] = sel_lab[i * NK + 512 + t];
  labLds[1024 + t] = sel_lab[inxt * NK + t];
  labLds[1536 + t] = sel_lab[inxt * NK + 512 + t];
  ASM_VMCNT0; ASM_LGKM0; MEMFENCE; BARRIER; MEMFENCE;

  short8 afrag[2][8];
#pragma unroll
  for (int rt = 0; rt < 2; ++rt) {
    const int arow = rw * 32 + rt * 16 + lr;
#pragma unroll
    for (int ks = 0; ks < 8; ++ks) {
      int ch = ks * 4 + lg;
      afrag[rt][ks] = *(const short8*)(buf[0] + arow * 256 + ((ch ^ (arow & 15)) << 3));
    }
  }
  int rlab[2][4];
#pragma unroll
  for (int rt = 0; rt < 2; ++rt)
#pragma unroll
    for (int jj = 0; jj < 4; ++jj) {
      int L = labLds[strip * 64 + rw * 32 + rt * 16 + 4 * lg + jj];
      rlab[rt][jj] = (L == IGN) ? -1 : L;
    }
  ASM_LGKM0; SCHEDB; MEMFENCE; BARRIER; MEMFENCE;   // buf0 free

  stage_round(0);
  stage_round(1);

  ASM_VMCNT8; MEMFENCE; BARRIER; MEMFENCE;     // round 0 ready

  float SA[2][4], NPr[2][4], PEr[2][4], ETr[2][4];
#pragma unroll
  for (int rt = 0; rt < 2; ++rt)
#pragma unroll
    for (int jj = 0; jj < 4; ++jj) { SA[rt][jj] = 0.f; NPr[rt][jj] = 0.f; PEr[rt][jj] = 0.f; ETr[rt][jj] = 0.f; }

  const int rs = strip >> 1;                    // diag round
  const bool dwave = ((ch4 >> 1) == (strip & 1));

  // ================= SELF rounds 0..7 =================
  for (int r = 0; r < 8; ++r) {
    int cl[2]; float cvf[2];
#pragma unroll
    for (int c2 = 0; c2 < 2; ++c2) {
      int L = labLds[r * 128 + ch4 * 32 + c2 * 16 + lr];
      cl[c2] = (L == IGN) ? -2 : L;
      cvf[c2] = (L == IGN) ? 0.f : 1.f;
    }

    const short* bb = buf[r & 1];
    f32x4 acc[2][2];
#pragma unroll
    for (int rt = 0; rt < 2; ++rt)
#pragma unroll
      for (int c2 = 0; c2 < 2; ++c2) acc[rt][c2] = f32x4{0.f, 0.f, 0.f, 0.f};
#pragma unroll
    for (int ks = 0; ks < 8; ++ks) {
      int ch = ks * 4 + lg;
      short8 b0, b1;
      {
        int br0 = ch4 * 32 + lr, br1 = ch4 * 32 + 16 + lr;
        b0 = *(const short8*)(bb + br0 * 256 + ((ch ^ (br0 & 15)) << 3));
        b1 = *(const short8*)(bb + br1 * 256 + ((ch ^ (br1 & 15)) << 3));
      }
      acc[0][0] = __builtin_amdgcn_mfma_f32_16x16x32_bf16(afrag[0][ks], b0, acc[0][0], 0, 0, 0);
      acc[0][1] = __builtin_amdgcn_mfma_f32_16x16x32_bf16(afrag[0][ks], b1, acc[0][1], 0, 0, 0);
      acc[1][0] = __builtin_amdgcn_mfma_f32_16x16x32_bf16(afrag[1][ks], b0, acc[1][0], 0, 0, 0);
      acc[1][1] = __builtin_amdgcn_mfma_f32_16x16x32_bf16(afrag[1][ks], b1, acc[1][1], 0, 0, 0);
    }

    const bool isdiag = (r == rs) && dwave;
#pragma unroll
    for (int rt = 0; rt < 2; ++rt)
#pragma unroll
      for (int c2 = 0; c2 < 2; ++c2) {
        const int clc = cl[c2]; const float cvc = cvf[c2];
        const int gc = r * 128 + ch4 * 32 + c2 * 16 + lr;
        const int grb = strip * 64 + rw * 32 + rt * 16 + 4 * lg;
#pragma unroll
        for (int jj = 0; jj < 4; ++jj) {
          float a = acc[rt][c2][jj];
          float E = fexp2(a);
          float Ev = cvc * E;
          float pm = (rlab[rt][jj] == clc) ? 1.f : 0.f;
          if (isdiag) {
            bool ok = (grb + jj) != gc;
            pm = ok ? pm : 0.f;
            Ev = ok ? Ev : 0.f;
          }
          SA[rt][jj] += pm * a; NPr[rt][jj] += pm;
          PEr[rt][jj] += pm * Ev; ETr[rt][jj] += Ev;
        }
      }

    MEMFENCE; BARRIER; MEMFENCE;
    stage_round(r + 2);
    ASM_VMCNT8;
    MEMFENCE; BARRIER; MEMFENCE;
  }

  // ---- self fold -> rredS ----
#pragma unroll
  for (int rt = 0; rt < 2; ++rt)
#pragma unroll
    for (int jj = 0; jj < 4; ++jj) {
      float a = SA[rt][jj], b4 = NPr[rt][jj], c4 = PEr[rt][jj], d4 = ETr[rt][jj];
#pragma unroll
      for (int m = 1; m <= 8; m <<= 1) {
        a += __shfl_xor(a, m); b4 += __shfl_xor(b4, m);
        c4 += __shfl_xor(c4, m); d4 += __shfl_xor(d4, m);
      }
      if (lr == 0) rredS[ch4][rw * 32 + rt * 16 + 4 * lg + jj] = make_float4(a, b4, c4, d4);
    }

  float SX[2][4], NX[2][4], PX[2][4];
#pragma unroll
  for (int rt = 0; rt < 2; ++rt)
#pragma unroll
    for (int jj = 0; jj < 4; ++jj) { SX[rt][jj] = 0.f; NX[rt][jj] = 0.f; PX[rt][jj] = 0.f; }

  // ================= CROSS rounds 8..15 =================
  for (int r = 8; r < 16; ++r) {
    int cl[2];
#pragma unroll
    for (int c2 = 0; c2 < 2; ++c2) {
      int L = labLds[1024 + (r & 7) * 128 + ch4 * 32 + c2 * 16 + lr];
      cl[c2] = (L == IGN) ? -2 : L;
    }

    const short* bb = buf[r & 1];
    f32x4 acc[2][2];
#pragma unroll
    for (int rt = 0; rt < 2; ++rt)
#pragma unroll
      for (int c2 = 0; c2 < 2; ++c2) acc[rt][c2] = f32x4{0.f, 0.f, 0.f, 0.f};
#pragma unroll
    for (int ks = 0; ks < 8; ++ks) {
      int ch = ks * 4 + lg;
      short8 b0, b1;
      {
        int br0 = ch4 * 32 + lr, br1 = ch4 * 32 + 16 + lr;
        b0 = *(const short8*)(bb + br0 * 256 + ((ch ^ (br0 & 15)) << 3));
        b1 = *(const short8*)(bb + br1 * 256 + ((ch ^ (br1 & 15)) << 3));
      }
      acc[0][0] = __builtin_amdgcn_mfma_f32_16x16x32_bf16(afrag[0][ks], b0, acc[0][0], 0, 0, 0);
      acc[0][1] = __builtin_amdgcn_mfma_f32_16x16x32_bf16(afrag[0][ks], b1, acc[0][1], 0, 0, 0);
      acc[1][0] = __builtin_amdgcn_mfma_f32_16x16x32_bf16(afrag[1][ks], b0, acc[1][0], 0, 0, 0);
      acc[1][1] = __builtin_amdgcn_mfma_f32_16x16x32_bf16(afrag[1][ks], b1, acc[1][1], 0, 0, 0);
    }

    float cS[2], cN[2], cE[2];
#pragma unroll
    for (int c2 = 0; c2 < 2; ++c2) { cS[c2] = 0.f; cN[c2] = 0.f; cE[c2] = 0.f; }
#pragma unroll
    for (int rt = 0; rt < 2; ++rt)
#pragma unroll
      for (int c2 = 0; c2 < 2; ++c2) {
        const int clc = cl[c2];
#pragma unroll
        for (int jj = 0; jj < 4; ++jj) {
          float a = acc[rt][c2][jj];
          float E = fexp2(a);
          float pm = (rlab[rt][jj] == clc) ? 1.f : 0.f;
          float pa = pm * a, pe = pm * E;
          SX[rt][jj] += pa; NX[rt][jj] += pm; PX[rt][jj] += pe;
          cS[c2] += pa; cN[c2] += pm; cE[c2] += pe;
        }
      }
#pragma unroll
    for (int c2 = 0; c2 < 2; ++c2) {
      cS[c2] += __shfl_xor(cS[c2], 16); cS[c2] += __shfl_xor(cS[c2], 32);
      cN[c2] += __shfl_xor(cN[c2], 16); cN[c2] += __shfl_xor(cN[c2], 32);
      cE[c2] += __shfl_xor(cE[c2], 16); cE[c2] += __shfl_xor(cE[c2], 32);
      if (lg == 0) colAcc[rw][ch4 * 32 + c2 * 16 + lr] = make_float4(cS[c2], cN[c2], cE[c2], 0.f);
    }
    ASM_LGKM0; SCHEDB;
    MEMFENCE; BARRIER; MEMFENCE;
    if (rw == 1 && lg == 0) {
#pragma unroll
      for (int c2 = 0; c2 < 2; ++c2) {
        int col = ch4 * 32 + c2 * 16 + lr;
        float4 o = colAcc[0][col];
        Cp[(i * 16 + strip) * NK + (r & 7) * 128 + col] =
            make_float4(cS[c2] + o.x, cN[c2] + o.y, (cE[c2] + o.z) * SFAC, 0.f);
      }
    }
    if (r < 14) { stage_round(r + 2); ASM_VMCNT8; MEMFENCE; BARRIER; MEMFENCE; }
    else if (r == 14) { ASM_VMCNT0; MEMFENCE; BARRIER; MEMFENCE; }
  }

  // ---- cross fold -> rredX ----
#pragma unroll
  for (int rt = 0; rt < 2; ++rt)
#pragma unroll
    for (int jj = 0; jj < 4; ++jj) {
      float a = SX[rt][jj], b4 = NX[rt][jj], c4 = PX[rt][jj];
#pragma unroll
      for (int m = 1; m <= 8; m <<= 1) {
        a += __shfl_xor(a, m); b4 += __shfl_xor(b4, m); c4 += __shfl_xor(c4, m);
      }
      if (lr == 0) rredX[ch4][rw * 32 + rt * 16 + 4 * lg + jj] = make_float4(a, b4, c4, 0.f);
    }
  __syncthreads();

  // ---- per-row pass: SNd/Rii writes + local a1 ----
  if (t < 64) {
    float4 sS = rredS[0][t], sX = rredX[0][t];
#pragma unroll
    for (int c4 = 1; c4 < 4; ++c4) {
      float4 u = rredS[c4][t], v = rredX[c4][t];
      sS.x += u.x; sS.y += u.y; sS.z += u.z; sS.w += u.w;
      sX.x += v.x; sX.y += v.y; sX.z += v.z;
    }
    float SNL = sS.w - sS.z;
    float SN = SNL * SFAC + 1e-8f;
    float LSN = __logf(SN), rSN = 1.f / SN;
    int g = i * NK + strip * 64 + t;
    SNd[g] = make_float2(LSN, rSN);
    Rii[g] = make_float4(sS.x, sS.y, sS.z * SFAC, 0.f);
    float pps = LN2 * (sS.x - CBIAS * sS.y) - sS.y * LSN - rSN * (sS.z * SFAC);
    float ppx = LN2 * (sX.x - CBIAS * sX.y) - sX.y * LSN - rSN * (sX.z * SFAC);
    float np1 = sS.y + sX.y;
    float an = 0.f, ac = 0.f;
    if (np1 > 0.f) { an = -(pps + ppx) / np1; ac = 1.f; }
#pragma unroll
    for (int m = 1; m <= 32; m <<= 1) { an += __shfl_xor(an, m); ac += __shfl_xor(ac, m); }
    if (t == 0) A1arr[i * 16 + strip] = make_float2(an, ac);
  }
  __syncthreads();

  // ---- counter dance ----
  if (t == 0) {
    __threadfence();
    int o1 = atomicAdd(&cnt[i], 1);
    int o2 = atomicAdd(&cnt[iprev], 1);
    fA = (o1 == 31); fB = (o2 == 31);
  }
  __syncthreads();

  auto pair_fold = [&](int p) {
    const int q = (p + 1) & 15;
    ACQ_AGENT;
    float an = 0.f, ac = 0.f;
    for (int r2 = t; r2 < NK; r2 += 512) {
      float4 rii = Rii[q * NK + r2];
      float2 sn = SNd[q * NK + r2];
      float cs = 0.f, cn = 0.f, ce = 0.f;
#pragma unroll
      for (int s2 = 0; s2 < 16; ++s2) {
        float4 c = Cp[(p * 16 + s2) * NK + r2];
        cs += c.x; cn += c.y; ce += c.z;
      }
      float ppc = LN2 * (cs - CBIAS * cn) - cn * sn.x - sn.y * ce;
      float ppi = LN2 * (rii.x - CBIAS * rii.y) - rii.y * sn.x - sn.y * rii.z;
      float np2 = rii.y + cn;
      if (np2 > 0.f) { an -= (ppi + ppc) / np2; ac += 1.f; }
    }
#pragma unroll
    for (int m = 1; m <= 32; m <<= 1) { an += __shfl_xor(an, m); ac += __shfl_xor(ac, m); }
    if (lane == 0) fold2[w] = make_float2(an, ac);
    __syncthreads();
    if (t == 0) {
      float a2n = 0.f, a2c = 0.f;
#pragma unroll
      for (int k2 = 0; k2 < 8; ++k2) { a2n += fold2[k2].x; a2c += fold2[k2].y; }
      float a1n = 0.f, a1c = 0.f;
#pragma unroll
      for (int s2 = 0; s2 < 16; ++s2) {
        float2 a = A1arr[q * 16 + s2];
        a1n += a.x; a1c += a.y;
      }
      Aimg[q] = make_float2(a1n + a2n, a1c + a2c);
      __threadfence();
      int f = atomicAdd(findone, 1);
      if (f == NB - 1) {
        ACQ_AGENT;
        float v = 0.f;
#pragma unroll
        for (int im = 0; im < NB; ++im) {
          float2 gg = Aimg[im];
          v += gg.x / fmaxf(gg.y, 1.f);
        }
        out[0] = v / (float)NB;
      }
    }
    __syncthreads();
  };

  if (fA) pair_fold(i);
  if (fB) pair_fold(iprev);
}

}  // namespace

extern "C" void kernel_launch(void* const* d_in, const int* in_sizes, int n_in,
                              void* d_out, int out_size, void* d_ws, size_t ws_size,
                              hipStream_t stream) {
  (void)in_sizes; (void)n_in; (void)out_size; (void)ws_size;
  const float* feats  = (const float*)d_in[0];
  const int*   labels = (const int*)d_in[1];
  float* out = (float*)d_out;
  char* ws = (char*)d_ws;

  int* sel_lab = (int*)ws;                                       // 64 KB
  int* sel_idx = (int*)(ws + (64 << 10));                        // 64 KB
  unsigned short* SF = (unsigned short*)(ws + (128 << 10));      // 8 MB
  size_t off = (128 << 10) + (size_t)NB * NK * NC * 2;
  float2* SNd = (float2*)(ws + off);  off += (size_t)NB * NK * 8;       // 128 KB
  float4* Rii = (float4*)(ws + off);  off += (size_t)NB * NK * 16;      // 256 KB
  float4* Cp  = (float4*)(ws + off);  off += (size_t)NB * 16 * NK * 16; // 4 MB
  float2* A1arr = (float2*)(ws + off); off += (size_t)NB * 16 * 8;
  float2* Aimg = (float2*)(ws + off);  off += NB * 8;
  int* cnt = (int*)(ws + off);         off += 16 * 4;
  int* findone = (int*)(ws + off);

  pcl_sample<<<NB, 1024, 0, stream>>>(labels, sel_lab, sel_idx, cnt, findone);
  pcl_gather<<<256, 1024, 0, stream>>>(feats, sel_lab, sel_idx, SF);
  pcl_tiles<<<256, 512, 0, stream>>>(SF, sel_lab, SNd, Rii, Cp,
                                     A1arr, Aimg, cnt, findone, out);
}